// Round 1
// baseline (935.571 us; speedup 1.0000x reference)
//
#include <hip/hip_runtime.h>

#define BN 8
#define NN 4096
#define DD 256   // D_FULL
#define MM 256   // num features
#define DV 256   // value dim
#define CHUNK 256
#define NC (NN / CHUNK)   // 16 chunks per batch

// acc[4][16] += x4(rows) * w(cols mapped g*64 + tx*4 + 0..3)
__device__ __forceinline__ void fma_4x16(float (&acc)[4][16], const float4 xq,
                                         const float* __restrict__ wrow, const int tx)
{
    const float xr[4] = {xq.x, xq.y, xq.z, xq.w};
#pragma unroll
    for (int g = 0; g < 4; ++g) {
        const float4 w = *(const float4*)(wrow + g * 64 + tx * 4);
#pragma unroll
        for (int rr = 0; rr < 4; ++rr) {
            acc[rr][g * 4 + 0] = fmaf(xr[rr], w.x, acc[rr][g * 4 + 0]);
            acc[rr][g * 4 + 1] = fmaf(xr[rr], w.y, acc[rr][g * 4 + 1]);
            acc[rr][g * 4 + 2] = fmaf(xr[rr], w.z, acc[rr][g * 4 + 2]);
            acc[rr][g * 4 + 3] = fmaf(xr[rr], w.w, acc[rr][g * 4 + 3]);
        }
    }
}

// ---------------------------------------------------------------------------
// K1: phi = exp(proj - rowmax(proj)) / sqrt(M), proj = X @ omega^T
//     (the -0.5*||x||^2 term cancels against the row-max subtraction)
// grid: (B*N)/64 = 512 blocks, 256 threads. Block: 64 rows x all 256 cols.
// ---------------------------------------------------------------------------
__global__ __launch_bounds__(256) void phi_kernel(
    const float* __restrict__ X, const float* __restrict__ Om, float* __restrict__ Phi)
{
    const int tid = threadIdx.x;
    const int tx = tid & 15;
    const int ty = tid >> 4;
    const long r0 = (long)blockIdx.x * 64;

    __shared__ float x_s[32][68];    // [k][row], rows 272B -> float4-aligned
    __shared__ float w_s[32][260];   // [k][m]
    __shared__ float red[64][17];
    __shared__ float rowmax_s[64];

    float acc[4][16];
#pragma unroll
    for (int i = 0; i < 4; ++i)
#pragma unroll
        for (int j = 0; j < 16; ++j) acc[i][j] = 0.f;

    for (int kt = 0; kt < DD; kt += 32) {
        // X tile 64 rows x 32 k : transpose into x_s[k][row]
#pragma unroll
        for (int i = 0; i < 2; ++i) {
            const int l = i * 256 + tid;
            const int lr = l >> 3;
            const int lk = (l & 7) << 2;
            const float4 v = *(const float4*)(X + (r0 + lr) * DD + kt + lk);
            x_s[lk + 0][lr] = v.x; x_s[lk + 1][lr] = v.y;
            x_s[lk + 2][lr] = v.z; x_s[lk + 3][lr] = v.w;
        }
        // omega tile 256 m x 32 k : transpose into w_s[k][m]
#pragma unroll
        for (int i = 0; i < 8; ++i) {
            const int l = i * 256 + tid;
            const int lm = l >> 3;
            const int lk = (l & 7) << 2;
            const float4 v = *(const float4*)(Om + (long)lm * DD + kt + lk);
            w_s[lk + 0][lm] = v.x; w_s[lk + 1][lm] = v.y;
            w_s[lk + 2][lm] = v.z; w_s[lk + 3][lm] = v.w;
        }
        __syncthreads();
#pragma unroll
        for (int k = 0; k < 32; ++k) {
            const float4 xq = *(const float4*)&x_s[k][ty * 4];
            fma_4x16(acc, xq, &w_s[k][0], tx);
        }
        __syncthreads();
    }
    // row max over all 256 cols
#pragma unroll
    for (int rr = 0; rr < 4; ++rr) {
        float m = acc[rr][0];
#pragma unroll
        for (int j = 1; j < 16; ++j) m = fmaxf(m, acc[rr][j]);
        red[ty * 4 + rr][tx] = m;
    }
    __syncthreads();
    if (tid < 64) {
        float m = red[tid][0];
#pragma unroll
        for (int j = 1; j < 16; ++j) m = fmaxf(m, red[tid][j]);
        rowmax_s[tid] = m;
    }
    __syncthreads();
#pragma unroll
    for (int rr = 0; rr < 4; ++rr) {
        const float rm = rowmax_s[ty * 4 + rr];
#pragma unroll
        for (int g = 0; g < 4; ++g) {
            float4 o;
            o.x = __expf(acc[rr][g * 4 + 0] - rm) * 0.0625f;
            o.y = __expf(acc[rr][g * 4 + 1] - rm) * 0.0625f;
            o.z = __expf(acc[rr][g * 4 + 2] - rm) * 0.0625f;
            o.w = __expf(acc[rr][g * 4 + 3] - rm) * 0.0625f;
            *(float4*)(Phi + (r0 + ty * 4 + rr) * MM + g * 64 + tx * 4) = o;
        }
    }
}

// ---------------------------------------------------------------------------
// K2: per-chunk S_c[m][dv] = sum_k phi_k[k][m] * V[k][dv];  z_c[m] = sum_k phi_k[k][m]
// grid: B*NC*4 = 512 blocks (4 m-tiles of 64), 256 threads.
// ---------------------------------------------------------------------------
__global__ __launch_bounds__(256) void state_kernel(
    const float* __restrict__ PhiK, const float* __restrict__ V,
    float* __restrict__ S, float* __restrict__ Z)
{
    const int tid = threadIdx.x;
    const int tx = tid & 15;
    const int ty = tid >> 4;
    const int mt = blockIdx.x & 3;
    const int c  = (blockIdx.x >> 2) & (NC - 1);
    const int b  = blockIdx.x >> 6;
    const int m0 = mt * 64;
    const long rowbase = (long)b * NN + (long)c * CHUNK;

    __shared__ float x_s[32][68];    // [k][m-local]
    __shared__ float w_s[32][260];   // [k][dv]

    float acc[4][16];
#pragma unroll
    for (int i = 0; i < 4; ++i)
#pragma unroll
        for (int j = 0; j < 16; ++j) acc[i][j] = 0.f;
    float zacc = 0.f;

    for (int kt = 0; kt < CHUNK; kt += 32) {
#pragma unroll
        for (int i = 0; i < 2; ++i) {
            const int l = i * 256 + tid;
            const int lk = l >> 4;
            const int lm = (l & 15) << 2;
            const float4 v = *(const float4*)(PhiK + (rowbase + kt + lk) * MM + m0 + lm);
            *(float4*)&x_s[lk][lm] = v;
        }
#pragma unroll
        for (int i = 0; i < 8; ++i) {
            const int l = i * 256 + tid;
            const int lk = l >> 6;
            const int ldv = (l & 63) << 2;
            const float4 v = *(const float4*)(V + (rowbase + kt + lk) * DV + ldv);
            *(float4*)&w_s[lk][ldv] = v;
        }
        __syncthreads();
        if (tid < 64) {
#pragma unroll
            for (int k = 0; k < 32; ++k) zacc += x_s[k][tid];
        }
#pragma unroll
        for (int k = 0; k < 32; ++k) {
            const float4 xq = *(const float4*)&x_s[k][ty * 4];
            fma_4x16(acc, xq, &w_s[k][0], tx);
        }
        __syncthreads();
    }
    const long sbase = ((long)(b * NC + c) * MM + m0) * DV;
#pragma unroll
    for (int rr = 0; rr < 4; ++rr)
#pragma unroll
        for (int g = 0; g < 4; ++g) {
            const float4 o = make_float4(acc[rr][g * 4 + 0], acc[rr][g * 4 + 1],
                                         acc[rr][g * 4 + 2], acc[rr][g * 4 + 3]);
            *(float4*)(S + sbase + (long)(ty * 4 + rr) * DV + g * 64 + tx * 4) = o;
        }
    if (tid < 64) Z[(long)(b * NC + c) * MM + m0 + tid] = zacc;
}

// ---------------------------------------------------------------------------
// K3: in-place exclusive prefix over chunks for S and z.
// grid: B*M*DV/256 = 2048 blocks.
// ---------------------------------------------------------------------------
__global__ __launch_bounds__(256) void prefix_kernel(float* __restrict__ S, float* __restrict__ Z)
{
    const long idx = (long)blockIdx.x * 256 + threadIdx.x;   // < B*M*DV = 524288
    const int b = (int)(idx >> 16);
    const int r = (int)(idx & 65535);
    float run = 0.f;
#pragma unroll
    for (int c = 0; c < NC; ++c) {
        const long off = ((long)(b * NC + c) << 16) + r;
        const float v = S[off];
        S[off] = run;
        run += v;
    }
    if (idx < BN * MM) {
        const int b2 = (int)(idx >> 8);
        const int m = (int)(idx & 255);
        float rz = 0.f;
#pragma unroll
        for (int c = 0; c < NC; ++c) {
            const long off = (long)(b2 * NC + c) * MM + m;
            const float v = Z[off];
            Z[off] = rz;
            rz += v;
        }
    }
}

// ---------------------------------------------------------------------------
// K4: out[i] = (phi_q[i] @ S_pre + sum_{j<=i in chunk} A[i][j] V[j])
//             / max(phi_q[i].z_pre + sum_{j<=i} A[i][j], 1e-6)
// grid: B*NC*4 = 512 blocks (4 row-tiles of 64 per chunk), 256 threads.
// LDS regions (aliased):
//   ldsA (17408B): a_s[64][68]  | phase3 q2_s[32][68]
//   ldsB (33280B): phase1 q_s[32][68]+pk_s[32][68] | phase2 v_s[32][260] | phase3 s_s[32][260]
// ---------------------------------------------------------------------------
__global__ __launch_bounds__(256) void out_kernel(
    const float* __restrict__ PhiQ, const float* __restrict__ PhiK,
    const float* __restrict__ V, const float* __restrict__ S,
    const float* __restrict__ Z, float* __restrict__ Out)
{
    const int tid = threadIdx.x;
    const int tx = tid & 15;
    const int ty = tid >> 4;
    const int it = blockIdx.x & 3;
    const int c  = (blockIdx.x >> 2) & (NC - 1);
    const int b  = blockIdx.x >> 6;
    const int i0 = it * 64;                                  // row-tile start within chunk
    const long chunk_row = (long)b * NN + (long)c * CHUNK;   // flat row of chunk start

    __shared__ __align__(16) char ldsA[17408];
    __shared__ __align__(16) char ldsB[33280];
    __shared__ float red[64][17];
    __shared__ float den_s[64];
    __shared__ float zs_s[32];

    float (*a_s)[68]  = (float(*)[68])ldsA;          // [64 j][64 li]
    float (*q2_s)[68] = (float(*)[68])ldsA;          // [32 m][64 li] (phase 3)
    float (*q_s)[68]  = (float(*)[68])ldsB;          // [32 m][64 li] (phase 1)
    float (*pk_s)[68] = (float(*)[68])(ldsB + 8704); // [32 m][64 j]  (phase 1)
    float (*v_s)[260] = (float(*)[260])ldsB;         // [32 k][256 dv] (phase 2/3)

    float out_acc[4][16];
#pragma unroll
    for (int i = 0; i < 4; ++i)
#pragma unroll
        for (int j = 0; j < 16; ++j) out_acc[i][j] = 0.f;
    float rsum[4] = {0.f, 0.f, 0.f, 0.f};

    for (int jt = 0; jt <= it; ++jt) {
        // ---- Phase 1: A_tile[li][j] = sum_m phi_q[i0+li][m] * phi_k[jt*64+j][m]
        float accA[4][4];
#pragma unroll
        for (int i = 0; i < 4; ++i)
#pragma unroll
            for (int j = 0; j < 4; ++j) accA[i][j] = 0.f;

        for (int mt = 0; mt < 8; ++mt) {
#pragma unroll
            for (int i = 0; i < 2; ++i) {
                const int l = i * 256 + tid;
                const int lr = l >> 3;
                const int lk = (l & 7) << 2;
                const float4 v = *(const float4*)(PhiQ + (chunk_row + i0 + lr) * MM + mt * 32 + lk);
                q_s[lk + 0][lr] = v.x; q_s[lk + 1][lr] = v.y;
                q_s[lk + 2][lr] = v.z; q_s[lk + 3][lr] = v.w;
                const float4 w = *(const float4*)(PhiK + (chunk_row + jt * 64 + lr) * MM + mt * 32 + lk);
                pk_s[lk + 0][lr] = w.x; pk_s[lk + 1][lr] = w.y;
                pk_s[lk + 2][lr] = w.z; pk_s[lk + 3][lr] = w.w;
            }
            __syncthreads();
#pragma unroll
            for (int k = 0; k < 32; ++k) {
                const float4 xq = *(const float4*)&q_s[k][ty * 4];
                const float4 wp = *(const float4*)&pk_s[k][tx * 4];
                const float xr[4] = {xq.x, xq.y, xq.z, xq.w};
                const float wr[4] = {wp.x, wp.y, wp.z, wp.w};
#pragma unroll
                for (int rr = 0; rr < 4; ++rr)
#pragma unroll
                    for (int jj = 0; jj < 4; ++jj)
                        accA[rr][jj] = fmaf(xr[rr], wr[jj], accA[rr][jj]);
            }
            __syncthreads();
        }
        // mask (causal), accumulate row sums, write A^T to LDS for phase 2
        const int ri_base = i0 + ty * 4;
        const int jbase = jt * 64 + tx * 4;
#pragma unroll
        for (int rr = 0; rr < 4; ++rr)
#pragma unroll
            for (int jj = 0; jj < 4; ++jj) {
                float v = accA[rr][jj];
                if (jbase + jj > ri_base + rr) v = 0.f;
                rsum[rr] += v;
                a_s[tx * 4 + jj][ty * 4 + rr] = v;
            }
        __syncthreads();
        // ---- Phase 2: out_acc += A_tile @ V[jt-tile]
        for (int half = 0; half < 2; ++half) {
#pragma unroll
            for (int i = 0; i < 8; ++i) {
                const int l = i * 256 + tid;
                const int lk = l >> 6;
                const int ldv = (l & 63) << 2;
                const float4 v = *(const float4*)(V + (chunk_row + jt * 64 + half * 32 + lk) * DV + ldv);
                *(float4*)&v_s[lk][ldv] = v;
            }
            __syncthreads();
#pragma unroll
            for (int k = 0; k < 32; ++k) {
                const int j = half * 32 + k;
                const float4 xa = *(const float4*)&a_s[j][ty * 4];
                fma_4x16(out_acc, xa, &v_s[k][0], tx);
            }
            __syncthreads();
        }
    }
    // reduce row sums -> den_s
#pragma unroll
    for (int rr = 0; rr < 4; ++rr) red[ty * 4 + rr][tx] = rsum[rr];
    __syncthreads();
    if (tid < 64) {
        float s = 0.f;
#pragma unroll
        for (int j = 0; j < 16; ++j) s += red[tid][j];
        den_s[tid] = s;
    }
    __syncthreads();
    // ---- Phase 3: out_acc += phi_q @ S_pre ; denz = phi_q . z_pre
    const long sbase = (long)(b * NC + c) * MM * DV;
    const long zbase = (long)(b * NC + c) * MM;
    float denz = 0.f;
    for (int mt = 0; mt < 8; ++mt) {
#pragma unroll
        for (int i = 0; i < 2; ++i) {
            const int l = i * 256 + tid;
            const int lr = l >> 3;
            const int lk = (l & 7) << 2;
            const float4 v = *(const float4*)(PhiQ + (chunk_row + i0 + lr) * MM + mt * 32 + lk);
            q2_s[lk + 0][lr] = v.x; q2_s[lk + 1][lr] = v.y;
            q2_s[lk + 2][lr] = v.z; q2_s[lk + 3][lr] = v.w;
        }
#pragma unroll
        for (int i = 0; i < 8; ++i) {
            const int l = i * 256 + tid;
            const int lk = l >> 6;
            const int ldv = (l & 63) << 2;
            const float4 v = *(const float4*)(S + sbase + (long)(mt * 32 + lk) * DV + ldv);
            *(float4*)&v_s[lk][ldv] = v;
        }
        if (tid < 32) zs_s[tid] = Z[zbase + mt * 32 + tid];
        __syncthreads();
#pragma unroll
        for (int k = 0; k < 32; ++k) {
            const float4 xq = *(const float4*)&q2_s[k][ty * 4];
            fma_4x16(out_acc, xq, &v_s[k][0], tx);
        }
        if (tid < 64) {
#pragma unroll
            for (int k = 0; k < 32; ++k) denz = fmaf(q2_s[k][tid], zs_s[k], denz);
        }
        __syncthreads();
    }
    if (tid < 64) den_s[tid] = fmaxf(den_s[tid] + denz, 1e-6f);
    __syncthreads();
    // ---- store
#pragma unroll
    for (int rr = 0; rr < 4; ++rr) {
        const float invd = 1.0f / den_s[ty * 4 + rr];
#pragma unroll
        for (int g = 0; g < 4; ++g) {
            const float4 o = make_float4(out_acc[rr][g * 4 + 0] * invd,
                                         out_acc[rr][g * 4 + 1] * invd,
                                         out_acc[rr][g * 4 + 2] * invd,
                                         out_acc[rr][g * 4 + 3] * invd);
            *(float4*)(Out + (chunk_row + i0 + ty * 4 + rr) * DV + g * 64 + tx * 4) = o;
        }
    }
}

extern "C" void kernel_launch(void* const* d_in, const int* in_sizes, int n_in,
                              void* d_out, int out_size, void* d_ws, size_t ws_size,
                              hipStream_t stream)
{
    const float* Q  = (const float*)d_in[0];
    const float* K  = (const float*)d_in[1];
    const float* V  = (const float*)d_in[2];
    const float* Om = (const float*)d_in[3];
    float* out = (float*)d_out;

    float* phi_q = (float*)d_ws;                       // B*N*M
    float* phi_k = phi_q + (size_t)BN * NN * MM;       // B*N*M
    float* S     = phi_k + (size_t)BN * NN * MM;       // B*NC*M*DV
    float* Z     = S + (size_t)BN * NC * MM * DV;      // B*NC*M

    phi_kernel<<<dim3((BN * NN) / 64), dim3(256), 0, stream>>>(Q, Om, phi_q);
    phi_kernel<<<dim3((BN * NN) / 64), dim3(256), 0, stream>>>(K, Om, phi_k);
    state_kernel<<<dim3(BN * NC * 4), dim3(256), 0, stream>>>(phi_k, V, S, Z);
    prefix_kernel<<<dim3((BN * MM * DV) / 256), dim3(256), 0, stream>>>(S, Z);
    out_kernel<<<dim3(BN * NC * 4), dim3(256), 0, stream>>>(phi_q, phi_k, V, S, Z, out);
}

// Round 2
// 329.534 us; speedup vs baseline: 2.8391x; 2.8391x over previous
//
#include <hip/hip_runtime.h>

#define BN 8
#define NN 4096
#define DD 256   // D_FULL
#define MM 256   // num features
#define DV 256   // value dim
#define CHUNK 256
#define NC (NN / CHUNK)   // 16 chunks per batch

using f32x4 = __attribute__((ext_vector_type(4))) float;
using s16x8 = __attribute__((ext_vector_type(8))) short;

#define MFMA16(a, b, c) __builtin_amdgcn_mfma_f32_16x16x32_bf16(a, b, c, 0, 0, 0)

__device__ __forceinline__ unsigned short f2bf(float x) {
    union { float f; unsigned int u; } v; v.f = x;
    unsigned int r = v.u + 0x7FFF + ((v.u >> 16) & 1);   // RNE
    return (unsigned short)(r >> 16);
}
__device__ __forceinline__ float bf2f(unsigned short u) {
    union { unsigned int u; float f; } v; v.u = ((unsigned int)u) << 16;
    return v.f;
}

// ---------------------------------------------------------------------------
// K1: phi = exp(proj - rowmax(proj)) / 16, proj = X @ omega^T   (fp32 VALU)
// bf16 output; optional per-chunk column sums z (atomicAdd, Z pre-zeroed).
// grid 512 blocks x 256 thr; block = 64 rows x 256 cols.
// ---------------------------------------------------------------------------
__global__ __launch_bounds__(256) void phi_f32(
    const float* __restrict__ X, const float* __restrict__ Om,
    unsigned short* __restrict__ Phi, float* __restrict__ Zp)
{
    const int tid = threadIdx.x;
    const int tx = tid & 15;
    const int ty = tid >> 4;
    const long r0 = (long)blockIdx.x * 64;

    __shared__ float x_s[32][68];
    __shared__ float w_s[32][260];
    __shared__ float red[64][17];
    __shared__ float rowmax_s[64];

    float acc[4][16];
#pragma unroll
    for (int i = 0; i < 4; ++i)
#pragma unroll
        for (int j = 0; j < 16; ++j) acc[i][j] = 0.f;

    for (int kt = 0; kt < DD; kt += 32) {
#pragma unroll
        for (int i = 0; i < 2; ++i) {
            const int l = i * 256 + tid;
            const int lr = l >> 3;
            const int lk = (l & 7) << 2;
            const float4 v = *(const float4*)(X + (r0 + lr) * DD + kt + lk);
            x_s[lk + 0][lr] = v.x; x_s[lk + 1][lr] = v.y;
            x_s[lk + 2][lr] = v.z; x_s[lk + 3][lr] = v.w;
        }
#pragma unroll
        for (int i = 0; i < 8; ++i) {
            const int l = i * 256 + tid;
            const int lm = l >> 3;
            const int lk = (l & 7) << 2;
            const float4 v = *(const float4*)(Om + (long)lm * DD + kt + lk);
            w_s[lk + 0][lm] = v.x; w_s[lk + 1][lm] = v.y;
            w_s[lk + 2][lm] = v.z; w_s[lk + 3][lm] = v.w;
        }
        __syncthreads();
#pragma unroll
        for (int k = 0; k < 32; ++k) {
            const float4 xq = *(const float4*)&x_s[k][ty * 4];
            const float xr[4] = {xq.x, xq.y, xq.z, xq.w};
#pragma unroll
            for (int g = 0; g < 4; ++g) {
                const float4 w = *(const float4*)&w_s[k][g * 64 + tx * 4];
#pragma unroll
                for (int rr = 0; rr < 4; ++rr) {
                    acc[rr][g * 4 + 0] = fmaf(xr[rr], w.x, acc[rr][g * 4 + 0]);
                    acc[rr][g * 4 + 1] = fmaf(xr[rr], w.y, acc[rr][g * 4 + 1]);
                    acc[rr][g * 4 + 2] = fmaf(xr[rr], w.z, acc[rr][g * 4 + 2]);
                    acc[rr][g * 4 + 3] = fmaf(xr[rr], w.w, acc[rr][g * 4 + 3]);
                }
            }
        }
        __syncthreads();
    }
    // row max over 256 cols
#pragma unroll
    for (int rr = 0; rr < 4; ++rr) {
        float m = acc[rr][0];
#pragma unroll
        for (int j = 1; j < 16; ++j) m = fmaxf(m, acc[rr][j]);
        red[ty * 4 + rr][tx] = m;
    }
    __syncthreads();
    if (tid < 64) {
        float m = red[tid][0];
#pragma unroll
        for (int j = 1; j < 16; ++j) m = fmaxf(m, red[tid][j]);
        rowmax_s[tid] = m;
    }
    __syncthreads();
    // exp, bf16 store (keep fp32 values in acc for the z path)
#pragma unroll
    for (int rr = 0; rr < 4; ++rr) {
        const float rm = rowmax_s[ty * 4 + rr];
#pragma unroll
        for (int g = 0; g < 4; ++g) {
            float p0 = __expf(acc[rr][g * 4 + 0] - rm) * 0.0625f;
            float p1 = __expf(acc[rr][g * 4 + 1] - rm) * 0.0625f;
            float p2 = __expf(acc[rr][g * 4 + 2] - rm) * 0.0625f;
            float p3 = __expf(acc[rr][g * 4 + 3] - rm) * 0.0625f;
            acc[rr][g * 4 + 0] = p0; acc[rr][g * 4 + 1] = p1;
            acc[rr][g * 4 + 2] = p2; acc[rr][g * 4 + 3] = p3;
            uint2 o;
            o.x = (unsigned)f2bf(p0) | ((unsigned)f2bf(p1) << 16);
            o.y = (unsigned)f2bf(p2) | ((unsigned)f2bf(p3) << 16);
            *(uint2*)(Phi + (r0 + ty * 4 + rr) * MM + g * 64 + tx * 4) = o;
        }
    }
    if (Zp) {
        float* colred = &w_s[0][0];   // reuse w_s (8320 floats >= 256*16)
#pragma unroll
        for (int g = 0; g < 4; ++g)
#pragma unroll
            for (int cc = 0; cc < 4; ++cc) {
                const int m = g * 64 + tx * 4 + cc;
                float s = acc[0][g * 4 + cc] + acc[1][g * 4 + cc]
                        + acc[2][g * 4 + cc] + acc[3][g * 4 + cc];
                colred[m * 16 + ty] = s;
            }
        __syncthreads();
        {
            float z = 0.f;
#pragma unroll
            for (int t = 0; t < 16; ++t) z += colred[tid * 16 + t];
            const int b = blockIdx.x >> 6;
            const int c = (blockIdx.x >> 2) & 15;
            atomicAdd(&Zp[((b * NC + c) << 8) + tid], z);
        }
    }
}

// ---------------------------------------------------------------------------
// T1: V fp32 [B*N][256] -> VT bf16 [B][256][N]
// grid (B*N/64)*4 = 2048 blocks
// ---------------------------------------------------------------------------
__global__ __launch_bounds__(256) void transpose_v(
    const float* __restrict__ V, unsigned short* __restrict__ VT)
{
    const int tid = threadIdx.x;
    const int ct = blockIdx.x & 3;                 // dv tile of 64
    const long r0 = (long)(blockIdx.x >> 2) * 64;  // flat row
    const int b = (int)(r0 >> 12);
    const int n0 = (int)(r0 & (NN - 1));
    __shared__ unsigned short T[64][72];
    const int rr = tid >> 4, cs = tid & 15;
#pragma unroll
    for (int p = 0; p < 4; ++p) {
        const int r = p * 16 + rr;
        const float4 v = *(const float4*)(V + (r0 + r) * DV + ct * 64 + cs * 4);
        T[cs * 4 + 0][r] = f2bf(v.x); T[cs * 4 + 1][r] = f2bf(v.y);
        T[cs * 4 + 2][r] = f2bf(v.z); T[cs * 4 + 3][r] = f2bf(v.w);
    }
    __syncthreads();
    const int cl = tid >> 3, ns = tid & 7;
#pragma unroll
    for (int p = 0; p < 2; ++p) {
        const int c = p * 32 + cl;
        *(uint4*)(VT + ((size_t)b * DV + ct * 64 + c) * NN + n0 + ns * 8) = *(uint4*)&T[c][ns * 8];
    }
}

// ---------------------------------------------------------------------------
// T2: PhiK bf16 [B*N][256] -> PhiKT bf16 [B][256][N]
// ---------------------------------------------------------------------------
__global__ __launch_bounds__(256) void transpose_bf(
    const unsigned short* __restrict__ Pk, unsigned short* __restrict__ PkT)
{
    const int tid = threadIdx.x;
    const int ct = blockIdx.x & 3;
    const long r0 = (long)(blockIdx.x >> 2) * 64;
    const int b = (int)(r0 >> 12);
    const int n0 = (int)(r0 & (NN - 1));
    __shared__ unsigned short T[64][72];
    const int rr = tid >> 3, cs = tid & 7;
#pragma unroll
    for (int p = 0; p < 2; ++p) {
        const int r = p * 32 + rr;
        unsigned short u[8];
        *(uint4*)u = *(const uint4*)(Pk + (r0 + r) * MM + ct * 64 + cs * 8);
#pragma unroll
        for (int k = 0; k < 8; ++k) T[cs * 8 + k][r] = u[k];
    }
    __syncthreads();
    const int cl = tid >> 3, ns = tid & 7;
#pragma unroll
    for (int p = 0; p < 2; ++p) {
        const int c = p * 32 + cl;
        *(uint4*)(PkT + ((size_t)b * MM + ct * 64 + c) * NN + n0 + ns * 8) = *(uint4*)&T[c][ns * 8];
    }
}

// ---------------------------------------------------------------------------
// K2: per-chunk ST_c[dv][m] = sum_kr V[kr][dv]*phi_k[kr][m]  (bf16 MFMA)
// A-frags from VT, B-frags from PhiKT, straight from global (no LDS).
// grid 512: 4 quadrants of 128x128 per (b,c); 4 waves of 64x64 each.
// ---------------------------------------------------------------------------
__global__ __launch_bounds__(256) void state_mfma(
    const unsigned short* __restrict__ VT, const unsigned short* __restrict__ PkT,
    unsigned short* __restrict__ ST)
{
    const int tid = threadIdx.x;
    const int w = tid >> 6;
    const int lane = tid & 63;
    const int col = lane & 15, quad = lane >> 4;
    const int q = blockIdx.x & 3;
    const int c = (blockIdx.x >> 2) & (NC - 1);
    const int b = blockIdx.x >> 6;
    const int dv0 = (q & 1) * 128 + (w & 1) * 64;
    const int m0  = (q >> 1) * 128 + (w >> 1) * 64;
    const unsigned short* Ab = VT  + (size_t)b * DV * NN + (size_t)c * CHUNK;
    const unsigned short* Bb = PkT + (size_t)b * MM * NN + (size_t)c * CHUNK;

    f32x4 acc[4][4] = {};
    for (int kr = 0; kr < CHUNK; kr += 32) {
        s16x8 a[4], bb[4];
#pragma unroll
        for (int t = 0; t < 4; ++t)
            a[t] = *(const s16x8*)(Ab + (size_t)(dv0 + t * 16 + col) * NN + kr + quad * 8);
#pragma unroll
        for (int t = 0; t < 4; ++t)
            bb[t] = *(const s16x8*)(Bb + (size_t)(m0 + t * 16 + col) * NN + kr + quad * 8);
#pragma unroll
        for (int i = 0; i < 4; ++i)
#pragma unroll
            for (int j = 0; j < 4; ++j) acc[i][j] = MFMA16(a[i], bb[j], acc[i][j]);
    }
    unsigned short* Sb = ST + (((size_t)(b * NC + c)) << 16);
#pragma unroll
    for (int i = 0; i < 4; ++i)
#pragma unroll
        for (int j = 0; j < 4; ++j)
#pragma unroll
            for (int r = 0; r < 4; ++r)
                Sb[(dv0 + i * 16 + quad * 4 + r) * MM + m0 + j * 16 + col] = f2bf(acc[i][j][r]);
}

// ---------------------------------------------------------------------------
// K3: in-place exclusive prefix over chunks: ST (bf16, fp32 running sum), Z (fp32)
// ---------------------------------------------------------------------------
__global__ __launch_bounds__(256) void prefix2(
    unsigned short* __restrict__ ST, float* __restrict__ Z)
{
    const long idx = (long)blockIdx.x * 256 + threadIdx.x;  // < B*DV*M = 524288
    const int b = (int)(idx >> 16);
    const int r = (int)(idx & 65535);
    float run = 0.f;
#pragma unroll
    for (int c = 0; c < NC; ++c) {
        const size_t off = (((size_t)(b * NC + c)) << 16) + r;
        const float v = bf2f(ST[off]);
        ST[off] = f2bf(run);
        run += v;
    }
    if (idx < BN * MM) {
        const int b2 = (int)(idx >> 8);
        const int m = (int)(idx & 255);
        float rz = 0.f;
#pragma unroll
        for (int c = 0; c < NC; ++c) {
            const size_t off = (size_t)(b2 * NC + c) * MM + m;
            const float v = Z[off];
            Z[off] = rz;
            rz += v;
        }
    }
}

// ---------------------------------------------------------------------------
// K4: out = (intra-chunk causal A@V + phi_q@S_pre) / (rowsum(A) + phi_q.z_pre)
// bf16 MFMA; frag loads from global; masked-A LDS round-trip (C->A layout).
// grid 512 (b, chunk, 4 row-tiles of 64); 4 waves = 4 dv-strips of 64.
// ---------------------------------------------------------------------------
__global__ __launch_bounds__(256) void out_mfma(
    const unsigned short* __restrict__ PhiQ, const unsigned short* __restrict__ PhiK,
    const unsigned short* __restrict__ VT, const unsigned short* __restrict__ ST,
    const float* __restrict__ Z, float* __restrict__ Out)
{
    const int tid = threadIdx.x;
    const int w = tid >> 6;
    const int lane = tid & 63;
    const int col = lane & 15, quad = lane >> 4;
    const int it = blockIdx.x & 3;
    const int c  = (blockIdx.x >> 2) & (NC - 1);
    const int b  = blockIdx.x >> 6;
    const size_t chunk_row = (size_t)b * NN + (size_t)c * CHUNK;
    const unsigned short* Qrow = PhiQ + (chunk_row + it * 64) * MM;   // [64][256]

    __shared__ unsigned short A_s[64][72];
    __shared__ float red[64][68];
    __shared__ float z_s[256];
    __shared__ float den_s[64];

    f32x4 oacc[4][4] = {};     // [i-tile][dv-tile]
    float rsum[4][4] = {};

    for (int jt = 0; jt <= it; ++jt) {
        const unsigned short* Krow = PhiK + (chunk_row + jt * 64) * MM;
        f32x4 accA[4] = {};
        for (int m = 0; m < MM; m += 32) {
            const s16x8 bk = *(const s16x8*)(Krow + (w * 16 + col) * MM + m + quad * 8);
#pragma unroll
            for (int t = 0; t < 4; ++t) {
                const s16x8 aq = *(const s16x8*)(Qrow + (t * 16 + col) * MM + m + quad * 8);
                accA[t] = MFMA16(aq, bk, accA[t]);
            }
        }
        __syncthreads();   // prior phase-2 A_s reads done
#pragma unroll
        for (int t = 0; t < 4; ++t)
#pragma unroll
            for (int r = 0; r < 4; ++r) {
                const int i_loc = t * 16 + quad * 4 + r;
                const int j_loc = w * 16 + col;
                float v = (jt * 64 + j_loc <= it * 64 + i_loc) ? accA[t][r] : 0.f;
                rsum[t][r] += v;
                A_s[i_loc][j_loc] = f2bf(v);
            }
        __syncthreads();
        // phase 2: oacc += A_tile @ V
#pragma unroll
        for (int ks = 0; ks < 64; ks += 32) {
            s16x8 av[4];
#pragma unroll
            for (int t = 0; t < 4; ++t)
                av[t] = *(const s16x8*)(&A_s[t * 16 + col][ks + quad * 8]);
#pragma unroll
            for (int t2 = 0; t2 < 4; ++t2) {
                const s16x8 bv = *(const s16x8*)(VT + ((size_t)b * DV + w * 64 + t2 * 16 + col) * NN
                                                 + (size_t)c * CHUNK + jt * 64 + ks + quad * 8);
#pragma unroll
                for (int t = 0; t < 4; ++t) oacc[t][t2] = MFMA16(av[t], bv, oacc[t][t2]);
            }
        }
    }
    // stash row-sum partials, stage z_pre
#pragma unroll
    for (int t = 0; t < 4; ++t)
#pragma unroll
        for (int r = 0; r < 4; ++r)
            red[t * 16 + quad * 4 + r][w * 16 + col] = rsum[t][r];
    z_s[tid] = Z[((size_t)(b * NC + c) << 8) + tid];
    __syncthreads();
    // phase 3: oacc += phi_q @ S_pre
    const unsigned short* Sb = ST + (((size_t)(b * NC + c)) << 16);
    for (int m = 0; m < MM; m += 32) {
        s16x8 aq[4];
#pragma unroll
        for (int t = 0; t < 4; ++t)
            aq[t] = *(const s16x8*)(Qrow + (t * 16 + col) * MM + m + quad * 8);
#pragma unroll
        for (int t2 = 0; t2 < 4; ++t2) {
            const s16x8 bs = *(const s16x8*)(Sb + (w * 64 + t2 * 16 + col) * MM + m + quad * 8);
#pragma unroll
            for (int t = 0; t < 4; ++t) oacc[t][t2] = MFMA16(aq[t], bs, oacc[t][t2]);
        }
    }
    // denominator z-dot: thread -> (row i, m-segment of 64)
    {
        const int i = tid & 63;
        const int seg = tid >> 6;
        float d = 0.f;
#pragma unroll
        for (int k = 0; k < 64; k += 8) {
            unsigned short u[8];
            *(uint4*)u = *(const uint4*)(Qrow + i * MM + seg * 64 + k);
#pragma unroll
            for (int x = 0; x < 8; ++x) d = fmaf(bf2f(u[x]), z_s[seg * 64 + k + x], d);
        }
        red[i][64 + seg] = d;
    }
    __syncthreads();
    if (tid < 64) {
        float s = 0.f;
#pragma unroll
        for (int j = 0; j < 68; ++j) s += red[tid][j];
        den_s[tid] = fmaxf(s, 1e-6f);
    }
    __syncthreads();
#pragma unroll
    for (int t = 0; t < 4; ++t)
#pragma unroll
        for (int r = 0; r < 4; ++r) {
            const int i_loc = t * 16 + quad * 4 + r;
            const float invd = 1.0f / den_s[i_loc];
#pragma unroll
            for (int t2 = 0; t2 < 4; ++t2)
                Out[(chunk_row + it * 64 + i_loc) * DV + w * 64 + t2 * 16 + col] = oacc[t][t2][r] * invd;
        }
}

extern "C" void kernel_launch(void* const* d_in, const int* in_sizes, int n_in,
                              void* d_out, int out_size, void* d_ws, size_t ws_size,
                              hipStream_t stream)
{
    const float* Q  = (const float*)d_in[0];
    const float* K  = (const float*)d_in[1];
    const float* V  = (const float*)d_in[2];
    const float* Om = (const float*)d_in[3];
    float* out = (float*)d_out;

    const size_t NM = (size_t)BN * NN * MM;       // 8.39M elems
    unsigned short* PhiQ  = (unsigned short*)d_ws;
    unsigned short* PhiK  = PhiQ + NM;
    unsigned short* PhiKT = PhiK + NM;
    unsigned short* VT    = PhiKT + NM;
    unsigned short* ST    = VT + NM;              // B*NC*DV*M
    float* Z = (float*)(ST + (size_t)BN * NC * DV * MM);

    hipMemsetAsync(Z, 0, (size_t)BN * NC * MM * sizeof(float), stream);
    phi_f32<<<dim3((BN * NN) / 64), dim3(256), 0, stream>>>(Q, Om, PhiQ, nullptr);
    phi_f32<<<dim3((BN * NN) / 64), dim3(256), 0, stream>>>(K, Om, PhiK, Z);
    transpose_v<<<dim3((BN * NN) / 64 * 4), dim3(256), 0, stream>>>(V, VT);
    transpose_bf<<<dim3((BN * NN) / 64 * 4), dim3(256), 0, stream>>>(PhiK, PhiKT);
    state_mfma<<<dim3(BN * NC * 4), dim3(256), 0, stream>>>(VT, PhiKT, ST);
    prefix2<<<dim3((BN * DV * MM) / 256), dim3(256), 0, stream>>>(ST, Z);
    out_mfma<<<dim3(BN * NC * 4), dim3(256), 0, stream>>>(PhiQ, PhiK, VT, ST, Z, out);
}

// Round 3
// 266.767 us; speedup vs baseline: 3.5071x; 1.2353x over previous
//
#include <hip/hip_runtime.h>

#define BN 8
#define NN 4096
#define DD 256   // D_FULL
#define MM 256   // num features
#define DV 256   // value dim
#define CHUNK 256
#define NC (NN / CHUNK)   // 16 chunks per batch

using f32x4 = __attribute__((ext_vector_type(4))) float;
using s16x8 = __attribute__((ext_vector_type(8))) short;

#define MFMA16(a, b, c) __builtin_amdgcn_mfma_f32_16x16x32_bf16(a, b, c, 0, 0, 0)

__device__ __forceinline__ unsigned short f2bf(float x) {
    union { float f; unsigned int u; } v; v.f = x;
    unsigned int r = v.u + 0x7FFF + ((v.u >> 16) & 1);   // RNE
    return (unsigned short)(r >> 16);
}
__device__ __forceinline__ float bf2f(unsigned short u) {
    union { unsigned int u; float f; } v; v.u = ((unsigned int)u) << 16;
    return v.f;
}

// ---------------------------------------------------------------------------
// K0: omega fp32 [256][256] -> hi/lo bf16 pair (row-major, B-operand ready)
// ---------------------------------------------------------------------------
__global__ __launch_bounds__(256) void omconv(
    const float* __restrict__ Om, unsigned short* __restrict__ OmH,
    unsigned short* __restrict__ OmL)
{
    const int i = blockIdx.x * 256 + threadIdx.x;      // 16384 threads x float4
    const float4 v = *(const float4*)(Om + (size_t)i * 4);
    const float xs[4] = {v.x, v.y, v.z, v.w};
    unsigned short h[4], l[4];
#pragma unroll
    for (int j = 0; j < 4; ++j) {
        h[j] = f2bf(xs[j]);
        l[j] = f2bf(xs[j] - bf2f(h[j]));
    }
    *(uint2*)(OmH + (size_t)i * 4) = *(uint2*)h;
    *(uint2*)(OmL + (size_t)i * 4) = *(uint2*)l;
}

// ---------------------------------------------------------------------------
// K1: phi = exp(X@Om^T - rowmax)/16 via bf16 MFMA with hi/lo split (3 terms).
// Writes Phi row-major; KPATH also writes PhiT [b][m][N] + per-chunk Z sums.
// grid 512 blocks x 256 thr; block = 64 rows x 256 cols (wave w: cols w*64+).
// ---------------------------------------------------------------------------
template<bool KPATH>
__global__ __launch_bounds__(256) void phi_mfma(
    const float* __restrict__ X, const unsigned short* __restrict__ OmH,
    const unsigned short* __restrict__ OmL, unsigned short* __restrict__ Phi,
    unsigned short* __restrict__ PhiT, float* __restrict__ Zp)
{
    const int tid = threadIdx.x;
    const int w = tid >> 6;
    const int lane = tid & 63;
    const int col = lane & 15, quad = lane >> 4;
    const long r0 = (long)blockIdx.x * 64;

    __shared__ __align__(16) char lds[33792];
    __shared__ float rowmax_s[64];
    short (*Xh)[40] = (short(*)[40])lds;                       // 5120 B
    short (*Xl)[40] = (short(*)[40])(lds + 5120);              // 5120 B
    float (*red)[67] = (float(*)[67])lds;                      // 17152 B
    unsigned short (*P)[264] = (unsigned short(*)[264])lds;    // 33792 B
    unsigned int* P32 = (unsigned int*)lds;

    f32x4 acc[4][4] = {};
    const int srow = tid >> 2;
    const int sk = (tid & 3) * 8;

    for (int kt = 0; kt < DD; kt += 32) {
        const float4 v0 = *(const float4*)(X + (r0 + srow) * DD + kt + sk);
        const float4 v1 = *(const float4*)(X + (r0 + srow) * DD + kt + sk + 4);
        const float xs[8] = {v0.x, v0.y, v0.z, v0.w, v1.x, v1.y, v1.z, v1.w};
        unsigned short h[8], l[8];
#pragma unroll
        for (int j = 0; j < 8; ++j) {
            h[j] = f2bf(xs[j]);
            l[j] = f2bf(xs[j] - bf2f(h[j]));
        }
        __syncthreads();
        *(uint4*)&Xh[srow][sk] = *(uint4*)h;
        *(uint4*)&Xl[srow][sk] = *(uint4*)l;
        __syncthreads();

        s16x8 ah[4], al[4], bh[4], bl[4];
#pragma unroll
        for (int t = 0; t < 4; ++t) {
            ah[t] = *(const s16x8*)&Xh[t * 16 + col][quad * 8];
            al[t] = *(const s16x8*)&Xl[t * 16 + col][quad * 8];
        }
#pragma unroll
        for (int ct = 0; ct < 4; ++ct) {
            const size_t off = (size_t)(w * 64 + ct * 16 + col) * DD + kt + quad * 8;
            bh[ct] = *(const s16x8*)(OmH + off);
            bl[ct] = *(const s16x8*)(OmL + off);
        }
#pragma unroll
        for (int t = 0; t < 4; ++t)
#pragma unroll
            for (int ct = 0; ct < 4; ++ct) {
                acc[t][ct] = MFMA16(ah[t], bh[ct], acc[t][ct]);
                acc[t][ct] = MFMA16(ah[t], bl[ct], acc[t][ct]);
                acc[t][ct] = MFMA16(al[t], bh[ct], acc[t][ct]);
            }
    }

    // ---- row max over 256 cols
    __syncthreads();
#pragma unroll
    for (int t = 0; t < 4; ++t)
#pragma unroll
        for (int r = 0; r < 4; ++r) {
            float m = acc[t][0][r];
#pragma unroll
            for (int ct = 1; ct < 4; ++ct) m = fmaxf(m, acc[t][ct][r]);
            red[t * 16 + quad * 4 + r][w * 16 + col] = m;
        }
    __syncthreads();
    if (tid < 64) {
        float m = red[tid][0];
#pragma unroll
        for (int j = 1; j < 64; ++j) m = fmaxf(m, red[tid][j]);
        rowmax_s[tid] = m;
    }
    __syncthreads();   // red region free after this

    // ---- exp epilogue -> P[n_local][m] (bf16), packed u32 writes (even cols)
#pragma unroll
    for (int t = 0; t < 4; ++t)
#pragma unroll
        for (int r = 0; r < 4; ++r) {
            const int n = t * 16 + quad * 4 + r;
            const float rm = rowmax_s[n];
#pragma unroll
            for (int ct = 0; ct < 4; ++ct) {
                const float val = __expf(acc[t][ct][r] - rm) * 0.0625f;
                const unsigned u = (unsigned)f2bf(val);
                const unsigned up = (unsigned)__shfl_xor((int)u, 1);
                if ((col & 1) == 0)
                    P32[n * 132 + w * 32 + ct * 8 + (col >> 1)] = u | (up << 16);
            }
        }
    __syncthreads();

    // ---- Phi row-major vectorized stores
    {
        const int t7 = tid & 7;
        const int nb = tid >> 3;     // 0..31
#pragma unroll
        for (int p2 = 0; p2 < 2; ++p2) {
            const int n = p2 * 32 + nb;
#pragma unroll
            for (int s = 0; s < 4; ++s)
                *(uint4*)(Phi + (r0 + n) * MM + t7 * 8 + s * 64) =
                    *(const uint4*)&P[n][t7 * 8 + s * 64];
        }
    }

    if (KPATH) {
        const int b = blockIdx.x >> 6;
        const int c = (blockIdx.x >> 2) & 15;
        const int n0 = (int)(r0 & (NN - 1));
        // PhiT [b][m][N]
        const int m0 = tid & 31;
        const int nsub = tid >> 5;   // 0..7
#pragma unroll
        for (int mi = 0; mi < 8; ++mi) {
            const int m = mi * 32 + m0;
            unsigned short u[8];
#pragma unroll
            for (int j = 0; j < 8; ++j) u[j] = P[nsub * 8 + j][m];
            *(uint4*)(PhiT + ((size_t)b * MM + m) * NN + n0 + nsub * 8) = *(uint4*)u;
        }
        // per-chunk column sums (bf16-consistent with MFMA path)
        float z = 0.f;
#pragma unroll
        for (int n = 0; n < 64; ++n) z += bf2f(P[n][tid]);
        atomicAdd(&Zp[((b * NC + c) << 8) + tid], z);
    }
}

// ---------------------------------------------------------------------------
// T1: V fp32 [B*N][256] -> VT bf16 [B][256][N]
// ---------------------------------------------------------------------------
__global__ __launch_bounds__(256) void transpose_v(
    const float* __restrict__ V, unsigned short* __restrict__ VT)
{
    const int tid = threadIdx.x;
    const int ct = blockIdx.x & 3;                 // dv tile of 64
    const long r0 = (long)(blockIdx.x >> 2) * 64;  // flat row
    const int b = (int)(r0 >> 12);
    const int n0 = (int)(r0 & (NN - 1));
    __shared__ unsigned short T[64][72];
    const int rr = tid >> 4, cs = tid & 15;
#pragma unroll
    for (int p = 0; p < 4; ++p) {
        const int r = p * 16 + rr;
        const float4 v = *(const float4*)(V + (r0 + r) * DV + ct * 64 + cs * 4);
        T[cs * 4 + 0][r] = f2bf(v.x); T[cs * 4 + 1][r] = f2bf(v.y);
        T[cs * 4 + 2][r] = f2bf(v.z); T[cs * 4 + 3][r] = f2bf(v.w);
    }
    __syncthreads();
    const int cl = tid >> 3, ns = tid & 7;
#pragma unroll
    for (int p = 0; p < 2; ++p) {
        const int c = p * 32 + cl;
        *(uint4*)(VT + ((size_t)b * DV + ct * 64 + c) * NN + n0 + ns * 8) = *(uint4*)&T[c][ns * 8];
    }
}

// ---------------------------------------------------------------------------
// K2: per-chunk ST_c[dv][m] = sum_kr V[kr][dv]*phi_k[kr][m]  (bf16 MFMA)
// ---------------------------------------------------------------------------
__global__ __launch_bounds__(256) void state_mfma(
    const unsigned short* __restrict__ VT, const unsigned short* __restrict__ PkT,
    unsigned short* __restrict__ ST)
{
    const int tid = threadIdx.x;
    const int w = tid >> 6;
    const int lane = tid & 63;
    const int col = lane & 15, quad = lane >> 4;
    const int q = blockIdx.x & 3;
    const int c = (blockIdx.x >> 2) & (NC - 1);
    const int b = blockIdx.x >> 6;
    const int dv0 = (q & 1) * 128 + (w & 1) * 64;
    const int m0  = (q >> 1) * 128 + (w >> 1) * 64;
    const unsigned short* Ab = VT  + (size_t)b * DV * NN + (size_t)c * CHUNK;
    const unsigned short* Bb = PkT + (size_t)b * MM * NN + (size_t)c * CHUNK;

    f32x4 acc[4][4] = {};
    for (int kr = 0; kr < CHUNK; kr += 32) {
        s16x8 a[4], bb[4];
#pragma unroll
        for (int t = 0; t < 4; ++t)
            a[t] = *(const s16x8*)(Ab + (size_t)(dv0 + t * 16 + col) * NN + kr + quad * 8);
#pragma unroll
        for (int t = 0; t < 4; ++t)
            bb[t] = *(const s16x8*)(Bb + (size_t)(m0 + t * 16 + col) * NN + kr + quad * 8);
#pragma unroll
        for (int i = 0; i < 4; ++i)
#pragma unroll
            for (int j = 0; j < 4; ++j) acc[i][j] = MFMA16(a[i], bb[j], acc[i][j]);
    }
    unsigned short* Sb = ST + (((size_t)(b * NC + c)) << 16);
#pragma unroll
    for (int i = 0; i < 4; ++i)
#pragma unroll
        for (int j = 0; j < 4; ++j)
#pragma unroll
            for (int r = 0; r < 4; ++r)
                Sb[(dv0 + i * 16 + quad * 4 + r) * MM + m0 + j * 16 + col] = f2bf(acc[i][j][r]);
}

// ---------------------------------------------------------------------------
// K3: in-place exclusive prefix over chunks: ST (bf16), Z (fp32)
// ---------------------------------------------------------------------------
__global__ __launch_bounds__(256) void prefix2(
    unsigned short* __restrict__ ST, float* __restrict__ Z)
{
    const long idx = (long)blockIdx.x * 256 + threadIdx.x;  // < B*DV*M = 524288
    const int b = (int)(idx >> 16);
    const int r = (int)(idx & 65535);
    float run = 0.f;
#pragma unroll
    for (int c = 0; c < NC; ++c) {
        const size_t off = (((size_t)(b * NC + c)) << 16) + r;
        const float v = bf2f(ST[off]);
        ST[off] = f2bf(run);
        run += v;
    }
    if (idx < BN * MM) {
        const int b2 = (int)(idx >> 8);
        const int m = (int)(idx & 255);
        float rz = 0.f;
#pragma unroll
        for (int c = 0; c < NC; ++c) {
            const size_t off = (size_t)(b2 * NC + c) * MM + m;
            const float v = Z[off];
            Z[off] = rz;
            rz += v;
        }
    }
}

// ---------------------------------------------------------------------------
// K4: out = (intra-chunk causal A@V + phi_q@S_pre) / (rowsum(A) + phi_q.z_pre)
// Longest-first it ordering: blocks with it=3 dispatched first.
// ---------------------------------------------------------------------------
__global__ __launch_bounds__(256) void out_mfma(
    const unsigned short* __restrict__ PhiQ, const unsigned short* __restrict__ PhiK,
    const unsigned short* __restrict__ VT, const unsigned short* __restrict__ ST,
    const float* __restrict__ Z, float* __restrict__ Out)
{
    const int tid = threadIdx.x;
    const int w = tid >> 6;
    const int lane = tid & 63;
    const int col = lane & 15, quad = lane >> 4;
    const int it = 3 - ((blockIdx.x >> 7) & 3);       // longest-first
    const int low = blockIdx.x & 127;
    const int c  = low & 15;
    const int b  = low >> 4;
    const size_t chunk_row = (size_t)b * NN + (size_t)c * CHUNK;
    const unsigned short* Qrow = PhiQ + (chunk_row + it * 64) * MM;   // [64][256]

    __shared__ unsigned short A_s[64][72];
    __shared__ float red[64][68];
    __shared__ float z_s[256];
    __shared__ float den_s[64];

    f32x4 oacc[4][4] = {};     // [i-tile][dv-tile]
    float rsum[4][4] = {};

    for (int jt = 0; jt <= it; ++jt) {
        const unsigned short* Krow = PhiK + (chunk_row + jt * 64) * MM;
        f32x4 accA[4] = {};
        for (int m = 0; m < MM; m += 32) {
            const s16x8 bk = *(const s16x8*)(Krow + (w * 16 + col) * MM + m + quad * 8);
#pragma unroll
            for (int t = 0; t < 4; ++t) {
                const s16x8 aq = *(const s16x8*)(Qrow + (t * 16 + col) * MM + m + quad * 8);
                accA[t] = MFMA16(aq, bk, accA[t]);
            }
        }
        __syncthreads();   // prior phase-2 A_s reads done
#pragma unroll
        for (int t = 0; t < 4; ++t)
#pragma unroll
            for (int r = 0; r < 4; ++r) {
                const int i_loc = t * 16 + quad * 4 + r;
                const int j_loc = w * 16 + col;
                float v = (jt * 64 + j_loc <= it * 64 + i_loc) ? accA[t][r] : 0.f;
                rsum[t][r] += v;
                A_s[i_loc][j_loc] = f2bf(v);
            }
        __syncthreads();
        // phase 2: oacc += A_tile @ V
#pragma unroll
        for (int ks = 0; ks < 64; ks += 32) {
            s16x8 av[4];
#pragma unroll
            for (int t = 0; t < 4; ++t)
                av[t] = *(const s16x8*)(&A_s[t * 16 + col][ks + quad * 8]);
#pragma unroll
            for (int t2 = 0; t2 < 4; ++t2) {
                const s16x8 bv = *(const s16x8*)(VT + ((size_t)b * DV + w * 64 + t2 * 16 + col) * NN
                                                 + (size_t)c * CHUNK + jt * 64 + ks + quad * 8);
#pragma unroll
                for (int t = 0; t < 4; ++t) oacc[t][t2] = MFMA16(av[t], bv, oacc[t][t2]);
            }
        }
    }
    // stash row-sum partials, stage z_pre
#pragma unroll
    for (int t = 0; t < 4; ++t)
#pragma unroll
        for (int r = 0; r < 4; ++r)
            red[t * 16 + quad * 4 + r][w * 16 + col] = rsum[t][r];
    z_s[tid] = Z[((size_t)(b * NC + c) << 8) + tid];
    __syncthreads();
    // phase 3: oacc += phi_q @ S_pre
    const unsigned short* Sb = ST + (((size_t)(b * NC + c)) << 16);
    for (int m = 0; m < MM; m += 32) {
        s16x8 aq[4];
#pragma unroll
        for (int t = 0; t < 4; ++t)
            aq[t] = *(const s16x8*)(Qrow + (t * 16 + col) * MM + m + quad * 8);
#pragma unroll
        for (int t2 = 0; t2 < 4; ++t2) {
            const s16x8 bs = *(const s16x8*)(Sb + (w * 64 + t2 * 16 + col) * MM + m + quad * 8);
#pragma unroll
            for (int t = 0; t < 4; ++t) oacc[t][t2] = MFMA16(aq[t], bs, oacc[t][t2]);
        }
    }
    // denominator z-dot: thread -> (row i, m-segment of 64)
    {
        const int i = tid & 63;
        const int seg = tid >> 6;
        float d = 0.f;
#pragma unroll
        for (int k = 0; k < 64; k += 8) {
            unsigned short u[8];
            *(uint4*)u = *(const uint4*)(Qrow + i * MM + seg * 64 + k);
#pragma unroll
            for (int x = 0; x < 8; ++x) d = fmaf(bf2f(u[x]), z_s[seg * 64 + k + x], d);
        }
        red[i][64 + seg] = d;
    }
    __syncthreads();
    if (tid < 64) {
        float s = 0.f;
#pragma unroll
        for (int j = 0; j < 68; ++j) s += red[tid][j];
        den_s[tid] = fmaxf(s, 1e-6f);
    }
    __syncthreads();
#pragma unroll
    for (int t = 0; t < 4; ++t)
#pragma unroll
        for (int r = 0; r < 4; ++r) {
            const int i_loc = t * 16 + quad * 4 + r;
            const float invd = 1.0f / den_s[i_loc];
#pragma unroll
            for (int t2 = 0; t2 < 4; ++t2)
                Out[(chunk_row + it * 64 + i_loc) * DV + w * 64 + t2 * 16 + col] = oacc[t][t2][r] * invd;
        }
}

extern "C" void kernel_launch(void* const* d_in, const int* in_sizes, int n_in,
                              void* d_out, int out_size, void* d_ws, size_t ws_size,
                              hipStream_t stream)
{
    const float* Q  = (const float*)d_in[0];
    const float* K  = (const float*)d_in[1];
    const float* V  = (const float*)d_in[2];
    const float* Om = (const float*)d_in[3];
    float* out = (float*)d_out;

    const size_t NM = (size_t)BN * NN * MM;       // 8.39M elems
    unsigned short* PhiQ  = (unsigned short*)d_ws;
    unsigned short* PhiK  = PhiQ + NM;
    unsigned short* PhiKT = PhiK + NM;
    unsigned short* VT    = PhiKT + NM;
    unsigned short* ST    = VT + NM;              // B*NC*DV*M
    unsigned short* OmH   = ST + (size_t)BN * NC * DV * MM;
    unsigned short* OmL   = OmH + (size_t)MM * DD;
    float* Z = (float*)(OmL + (size_t)MM * DD);

    hipMemsetAsync(Z, 0, (size_t)BN * NC * MM * sizeof(float), stream);
    omconv<<<dim3(64), dim3(256), 0, stream>>>(Om, OmH, OmL);
    phi_mfma<false><<<dim3((BN * NN) / 64), dim3(256), 0, stream>>>(Q, OmH, OmL, PhiQ, nullptr, nullptr);
    phi_mfma<true><<<dim3((BN * NN) / 64), dim3(256), 0, stream>>>(K, OmH, OmL, PhiK, PhiKT, Z);
    transpose_v<<<dim3((BN * NN) / 64 * 4), dim3(256), 0, stream>>>(V, VT);
    state_mfma<<<dim3(BN * NC * 4), dim3(256), 0, stream>>>(VT, PhiKT, ST);
    prefix2<<<dim3((BN * DV * MM) / 256), dim3(256), 0, stream>>>(ST, Z);
    out_mfma<<<dim3(BN * NC * 4), dim3(256), 0, stream>>>(PhiQ, PhiK, VT, ST, Z, out);
}

// Round 4
// 253.576 us; speedup vs baseline: 3.6895x; 1.0520x over previous
//
#include <hip/hip_runtime.h>

#define BN 8
#define NN 4096
#define DD 256   // D_FULL
#define MM 256   // num features
#define DV 256   // value dim
#define CHUNK 256
#define NC (NN / CHUNK)   // 16 chunks per batch

using f32x4 = __attribute__((ext_vector_type(4))) float;
using s16x8 = __attribute__((ext_vector_type(8))) short;

#define MFMA16(a, b, c) __builtin_amdgcn_mfma_f32_16x16x32_bf16(a, b, c, 0, 0, 0)

__device__ __forceinline__ unsigned short f2bf(float x) {
    union { float f; unsigned int u; } v; v.f = x;
    unsigned int r = v.u + 0x7FFF + ((v.u >> 16) & 1);   // RNE
    return (unsigned short)(r >> 16);
}
__device__ __forceinline__ float bf2f(unsigned short u) {
    union { unsigned int u; float f; } v; v.u = ((unsigned int)u) << 16;
    return v.f;
}

// ---------------------------------------------------------------------------
// K0: omega fp32 [256][256] -> hi/lo bf16 pair (row-major, B-operand ready)
// ---------------------------------------------------------------------------
__global__ __launch_bounds__(256) void omconv(
    const float* __restrict__ Om, unsigned short* __restrict__ OmH,
    unsigned short* __restrict__ OmL)
{
    const int i = blockIdx.x * 256 + threadIdx.x;
    const float4 v = *(const float4*)(Om + (size_t)i * 4);
    const float xs[4] = {v.x, v.y, v.z, v.w};
    unsigned short h[4], l[4];
#pragma unroll
    for (int j = 0; j < 4; ++j) {
        h[j] = f2bf(xs[j]);
        l[j] = f2bf(xs[j] - bf2f(h[j]));
    }
    *(uint2*)(OmH + (size_t)i * 4) = *(uint2*)h;
    *(uint2*)(OmL + (size_t)i * 4) = *(uint2*)l;
}

// ---------------------------------------------------------------------------
// K1: phi = exp(X@Om^T - rowmax)/16 via bf16 MFMA hi/lo (3 terms).
// v2: full X tile staged to LDS once (batched loads), barrier-free K loop,
// Om frags double-buffered. KPATH adds PhiT + per-chunk Z.
// ---------------------------------------------------------------------------
template<bool KPATH>
__global__ __launch_bounds__(256) void phi_mfma(
    const float* __restrict__ X, const unsigned short* __restrict__ OmH,
    const unsigned short* __restrict__ OmL, unsigned short* __restrict__ Phi,
    unsigned short* __restrict__ PhiT, float* __restrict__ Zp)
{
    const int tid = threadIdx.x;
    const int w = tid >> 6;
    const int lane = tid & 63;
    const int col = lane & 15, quad = lane >> 4;
    const long r0 = (long)blockIdx.x * 64;

    __shared__ __align__(16) char lds[67584];
    __shared__ float rowmax_s[64];
    short (*Xh)[264] = (short(*)[264])lds;                       // 33792 B
    short (*Xl)[264] = (short(*)[264])(lds + 33792);             // 33792 B
    unsigned short (*P)[264] = (unsigned short(*)[264])lds;      // aliases Xh (dead)
    unsigned int* P32 = (unsigned int*)lds;
    float (*red)[67] = (float(*)[67])(lds + 34048);              // aliases Xl (dead)

    // ---- stage X tile 64x256 fp32 -> Xh/Xl, all loads batched
    float4 xv[16];
#pragma unroll
    for (int i = 0; i < 16; ++i)
        xv[i] = *(const float4*)(X + r0 * DD + (size_t)(i * 256 + tid) * 4);
#pragma unroll
    for (int i = 0; i < 16; ++i) {
        const int f = i * 256 + tid;
        const int row = f >> 6;
        const int k4 = (f & 63) * 4;
        const float xs[4] = {xv[i].x, xv[i].y, xv[i].z, xv[i].w};
        unsigned short hh[4], ll[4];
#pragma unroll
        for (int j = 0; j < 4; ++j) {
            hh[j] = f2bf(xs[j]);
            ll[j] = f2bf(xs[j] - bf2f(hh[j]));
        }
        *(uint2*)&Xh[row][k4] = *(uint2*)hh;
        *(uint2*)&Xl[row][k4] = *(uint2*)ll;
    }
    __syncthreads();

    // ---- K loop: LDS A-frags, double-buffered Om B-frags, no barriers
    f32x4 acc[4][4] = {};
    s16x8 bh0[4], bl0[4], bh1[4], bl1[4];
#pragma unroll
    for (int ct = 0; ct < 4; ++ct) {
        const size_t off = (size_t)(w * 64 + ct * 16 + col) * DD + quad * 8;
        bh0[ct] = *(const s16x8*)(OmH + off);
        bl0[ct] = *(const s16x8*)(OmL + off);
    }
#pragma unroll
    for (int kt = 0; kt < 8; ++kt) {
        if (kt < 7) {
#pragma unroll
            for (int ct = 0; ct < 4; ++ct) {
                const size_t off = (size_t)(w * 64 + ct * 16 + col) * DD + (kt + 1) * 32 + quad * 8;
                bh1[ct] = *(const s16x8*)(OmH + off);
                bl1[ct] = *(const s16x8*)(OmL + off);
            }
        }
        s16x8 ah[4], al[4];
#pragma unroll
        for (int t = 0; t < 4; ++t) {
            ah[t] = *(const s16x8*)&Xh[t * 16 + col][kt * 32 + quad * 8];
            al[t] = *(const s16x8*)&Xl[t * 16 + col][kt * 32 + quad * 8];
        }
#pragma unroll
        for (int t = 0; t < 4; ++t)
#pragma unroll
            for (int ct = 0; ct < 4; ++ct) {
                acc[t][ct] = MFMA16(ah[t], bh0[ct], acc[t][ct]);
                acc[t][ct] = MFMA16(ah[t], bl0[ct], acc[t][ct]);
                acc[t][ct] = MFMA16(al[t], bh0[ct], acc[t][ct]);
            }
#pragma unroll
        for (int ct = 0; ct < 4; ++ct) { bh0[ct] = bh1[ct]; bl0[ct] = bl1[ct]; }
    }

    // ---- row max over 256 cols (red aliases Xl: barrier first)
    __syncthreads();
#pragma unroll
    for (int t = 0; t < 4; ++t)
#pragma unroll
        for (int r = 0; r < 4; ++r) {
            float m = acc[t][0][r];
#pragma unroll
            for (int ct = 1; ct < 4; ++ct) m = fmaxf(m, acc[t][ct][r]);
            red[t * 16 + quad * 4 + r][w * 16 + col] = m;
        }
    __syncthreads();
    if (tid < 64) {
        float m = red[tid][0];
#pragma unroll
        for (int j = 1; j < 64; ++j) m = fmaxf(m, red[tid][j]);
        rowmax_s[tid] = m;
    }
    __syncthreads();

    // ---- exp epilogue -> P[n][m] bf16 (P aliases Xh: dead)
#pragma unroll
    for (int t = 0; t < 4; ++t)
#pragma unroll
        for (int r = 0; r < 4; ++r) {
            const int n = t * 16 + quad * 4 + r;
            const float rm = rowmax_s[n];
#pragma unroll
            for (int ct = 0; ct < 4; ++ct) {
                const float val = __expf(acc[t][ct][r] - rm) * 0.0625f;
                const unsigned u = (unsigned)f2bf(val);
                const unsigned up = (unsigned)__shfl_xor((int)u, 1);
                if ((col & 1) == 0)
                    P32[n * 132 + w * 32 + ct * 8 + (col >> 1)] = u | (up << 16);
            }
        }
    __syncthreads();

    // ---- Phi row-major vectorized stores
    {
        const int t7 = tid & 7;
        const int nb = tid >> 3;
#pragma unroll
        for (int p2 = 0; p2 < 2; ++p2) {
            const int n = p2 * 32 + nb;
#pragma unroll
            for (int s = 0; s < 4; ++s)
                *(uint4*)(Phi + (r0 + n) * MM + t7 * 8 + s * 64) =
                    *(const uint4*)&P[n][t7 * 8 + s * 64];
        }
    }

    if (KPATH) {
        const int b = blockIdx.x >> 6;
        const int c = (blockIdx.x >> 2) & 15;
        const int n0 = (int)(r0 & (NN - 1));
        const int m0 = tid & 31;
        const int nsub = tid >> 5;
#pragma unroll
        for (int mi = 0; mi < 8; ++mi) {
            const int m = mi * 32 + m0;
            unsigned short u[8];
#pragma unroll
            for (int j = 0; j < 8; ++j) u[j] = P[nsub * 8 + j][m];
            *(uint4*)(PhiT + ((size_t)b * MM + m) * NN + n0 + nsub * 8) = *(uint4*)u;
        }
        float z = 0.f;
#pragma unroll
        for (int n = 0; n < 64; ++n) z += bf2f(P[n][tid]);
        atomicAdd(&Zp[((b * NC + c) << 8) + tid], z);
    }
}

// ---------------------------------------------------------------------------
// T1: V fp32 [B*N][256] -> VT bf16 [B][256][N]
// ---------------------------------------------------------------------------
__global__ __launch_bounds__(256) void transpose_v(
    const float* __restrict__ V, unsigned short* __restrict__ VT)
{
    const int tid = threadIdx.x;
    const int ct = blockIdx.x & 3;
    const long r0 = (long)(blockIdx.x >> 2) * 64;
    const int b = (int)(r0 >> 12);
    const int n0 = (int)(r0 & (NN - 1));
    __shared__ unsigned short T[64][72];
    const int rr = tid >> 4, cs = tid & 15;
#pragma unroll
    for (int p = 0; p < 4; ++p) {
        const int r = p * 16 + rr;
        const float4 v = *(const float4*)(V + (r0 + r) * DV + ct * 64 + cs * 4);
        T[cs * 4 + 0][r] = f2bf(v.x); T[cs * 4 + 1][r] = f2bf(v.y);
        T[cs * 4 + 2][r] = f2bf(v.z); T[cs * 4 + 3][r] = f2bf(v.w);
    }
    __syncthreads();
    const int cl = tid >> 3, ns = tid & 7;
#pragma unroll
    for (int p = 0; p < 2; ++p) {
        const int c = p * 32 + cl;
        *(uint4*)(VT + ((size_t)b * DV + ct * 64 + c) * NN + n0 + ns * 8) = *(uint4*)&T[c][ns * 8];
    }
}

// ---------------------------------------------------------------------------
// K2: per-chunk ST_c[dv][m] = sum_kr V[kr][dv]*phi_k[kr][m]  (bf16 MFMA)
// v2: depth-2 register dbuf, XCD-grouped grid (q = hi bits), 3 waves/EU.
// ---------------------------------------------------------------------------
__global__ __launch_bounds__(256, 3) void state_mfma(
    const unsigned short* __restrict__ VT, const unsigned short* __restrict__ PkT,
    unsigned short* __restrict__ ST)
{
    const int tid = threadIdx.x;
    const int w = tid >> 6;
    const int lane = tid & 63;
    const int col = lane & 15, quad = lane >> 4;
    const int q  = blockIdx.x >> 7;           // same (b,c) blocks 128 apart -> same XCD
    const int bc = blockIdx.x & 127;
    const int c  = bc & 15;
    const int b  = bc >> 4;
    const int dv0 = (q & 1) * 128 + (w & 1) * 64;
    const int m0  = (q >> 1) * 128 + (w >> 1) * 64;
    const unsigned short* Ab = VT  + (size_t)b * DV * NN + (size_t)c * CHUNK;
    const unsigned short* Bb = PkT + (size_t)b * MM * NN + (size_t)c * CHUNK;

    f32x4 acc[4][4] = {};
    s16x8 a0[4], b0[4], a1[4], b1[4];
#pragma unroll
    for (int t = 0; t < 4; ++t) {
        a0[t] = *(const s16x8*)(Ab + (size_t)(dv0 + t * 16 + col) * NN + quad * 8);
        b0[t] = *(const s16x8*)(Bb + (size_t)(m0 + t * 16 + col) * NN + quad * 8);
    }
#pragma unroll
    for (int kt = 0; kt < 8; ++kt) {
        if (kt < 7) {
#pragma unroll
            for (int t = 0; t < 4; ++t) {
                a1[t] = *(const s16x8*)(Ab + (size_t)(dv0 + t * 16 + col) * NN + (kt + 1) * 32 + quad * 8);
                b1[t] = *(const s16x8*)(Bb + (size_t)(m0 + t * 16 + col) * NN + (kt + 1) * 32 + quad * 8);
            }
        }
#pragma unroll
        for (int i = 0; i < 4; ++i)
#pragma unroll
            for (int j = 0; j < 4; ++j) acc[i][j] = MFMA16(a0[i], b0[j], acc[i][j]);
#pragma unroll
        for (int t = 0; t < 4; ++t) { a0[t] = a1[t]; b0[t] = b1[t]; }
    }
    unsigned short* Sb = ST + (((size_t)(b * NC + c)) << 16);
#pragma unroll
    for (int i = 0; i < 4; ++i)
#pragma unroll
        for (int j = 0; j < 4; ++j)
#pragma unroll
            for (int r = 0; r < 4; ++r)
                Sb[(dv0 + i * 16 + quad * 4 + r) * MM + m0 + j * 16 + col] = f2bf(acc[i][j][r]);
}

// ---------------------------------------------------------------------------
// K3: in-place exclusive prefix over chunks: ST (bf16), Z (fp32)
// ---------------------------------------------------------------------------
__global__ __launch_bounds__(256) void prefix2(
    unsigned short* __restrict__ ST, float* __restrict__ Z)
{
    const long idx = (long)blockIdx.x * 256 + threadIdx.x;
    const int b = (int)(idx >> 16);
    const int r = (int)(idx & 65535);
    float run = 0.f;
#pragma unroll
    for (int c = 0; c < NC; ++c) {
        const size_t off = (((size_t)(b * NC + c)) << 16) + r;
        const float v = bf2f(ST[off]);
        ST[off] = f2bf(run);
        run += v;
    }
    if (idx < BN * MM) {
        const int b2 = (int)(idx >> 8);
        const int m = (int)(idx & 255);
        float rz = 0.f;
#pragma unroll
        for (int c = 0; c < NC; ++c) {
            const size_t off = (size_t)(b2 * NC + c) * MM + m;
            const float v = Z[off];
            Z[off] = rz;
            rz += v;
        }
    }
}

// ---------------------------------------------------------------------------
// K4 v2: Q tile in LDS (staged once); batched/pipelined global frag loads.
// out = (intra causal A@V + phi_q@S_pre) / (rowsum(A) + phi_q.z_pre)
// ---------------------------------------------------------------------------
__global__ __launch_bounds__(256) void out_mfma(
    const unsigned short* __restrict__ PhiQ, const unsigned short* __restrict__ PhiK,
    const unsigned short* __restrict__ VT, const unsigned short* __restrict__ ST,
    const float* __restrict__ Z, float* __restrict__ Out)
{
    const int tid = threadIdx.x;
    const int w = tid >> 6;
    const int lane = tid & 63;
    const int col = lane & 15, quad = lane >> 4;
    const int it = 3 - (blockIdx.x >> 7);             // longest-first, same-(b,c) same-XCD
    const int low = blockIdx.x & 127;
    const int c  = low & 15;
    const int b  = low >> 4;
    const size_t chunk_row = (size_t)b * NN + (size_t)c * CHUNK;
    const unsigned short* Qrow = PhiQ + (chunk_row + it * 64) * MM;

    __shared__ unsigned short Qs[64][264];   // 33792 B
    __shared__ unsigned short A_s[64][72];   // 9216 B
    __shared__ float red[64][68];            // 17408 B
    __shared__ float z_s[256];
    __shared__ float den_s[64];

    // early issue: z + jt=0 K-frags + Q staging loads (all in flight together)
    const float zval = Z[((size_t)(b * NC + c) << 8) + tid];
    s16x8 bk0[8], bk1[8];
#pragma unroll
    for (int ms = 0; ms < 8; ++ms)
        bk0[ms] = *(const s16x8*)(PhiK + (chunk_row)*MM + (size_t)(w * 16 + col) * MM + ms * 32 + quad * 8);
    uint4 qv[8];
#pragma unroll
    for (int i = 0; i < 8; ++i)
        qv[i] = *((const uint4*)Qrow + i * 256 + tid);
    z_s[tid] = zval;
#pragma unroll
    for (int i = 0; i < 8; ++i) {
        const int f = i * 256 + tid;
        *(uint4*)&Qs[f >> 5][(f & 31) * 8] = qv[i];
    }
    __syncthreads();

    f32x4 oacc[4][4] = {};
    float rsum[4][4] = {};

    for (int jt = 0; jt <= it; ++jt) {
        // prefetch this jt's V-frags (consumed in phase 2)
        s16x8 bv[8];
        const unsigned short* Vbase = VT + ((size_t)b * DV + w * 64) * NN + (size_t)c * CHUNK + jt * 64;
#pragma unroll
        for (int ks2 = 0; ks2 < 2; ++ks2)
#pragma unroll
            for (int t2 = 0; t2 < 4; ++t2)
                bv[ks2 * 4 + t2] = *(const s16x8*)(Vbase + (size_t)(t2 * 16 + col) * NN + ks2 * 32 + quad * 8);
        // phase 1: A = phi_q . phi_k^T  (A-frags from LDS, K-frags preloaded)
        f32x4 accA[4] = {};
#pragma unroll
        for (int ms = 0; ms < 8; ++ms)
#pragma unroll
            for (int t = 0; t < 4; ++t) {
                const s16x8 aq = *(const s16x8*)&Qs[t * 16 + col][ms * 32 + quad * 8];
                accA[t] = MFMA16(aq, bk0[ms], accA[t]);
            }
        // prefetch next jt's K-frags
        if (jt < it) {
            const unsigned short* Krn = PhiK + (chunk_row + (jt + 1) * 64) * MM;
#pragma unroll
            for (int ms = 0; ms < 8; ++ms)
                bk1[ms] = *(const s16x8*)(Krn + (size_t)(w * 16 + col) * MM + ms * 32 + quad * 8);
        }
        __syncthreads();   // prior phase-2 A_s reads done
#pragma unroll
        for (int t = 0; t < 4; ++t)
#pragma unroll
            for (int r = 0; r < 4; ++r) {
                const int i_loc = t * 16 + quad * 4 + r;
                const int j_loc = w * 16 + col;
                float v = (jt * 64 + j_loc <= it * 64 + i_loc) ? accA[t][r] : 0.f;
                rsum[t][r] += v;
                A_s[i_loc][j_loc] = f2bf(v);
            }
        __syncthreads();
        // phase 2: oacc += A_tile @ V (A from LDS, V-frags preloaded)
#pragma unroll
        for (int ks2 = 0; ks2 < 2; ++ks2) {
            s16x8 av[4];
#pragma unroll
            for (int t = 0; t < 4; ++t)
                av[t] = *(const s16x8*)&A_s[t * 16 + col][ks2 * 32 + quad * 8];
#pragma unroll
            for (int t2 = 0; t2 < 4; ++t2)
#pragma unroll
                for (int t = 0; t < 4; ++t)
                    oacc[t][t2] = MFMA16(av[t], bv[ks2 * 4 + t2], oacc[t][t2]);
        }
#pragma unroll
        for (int ms = 0; ms < 8; ++ms) bk0[ms] = bk1[ms];
    }
    // stash row-sum partials
#pragma unroll
    for (int t = 0; t < 4; ++t)
#pragma unroll
        for (int r = 0; r < 4; ++r)
            red[t * 16 + quad * 4 + r][w * 16 + col] = rsum[t][r];

    // phase 3: oacc += phi_q @ S_pre  (S-frags depth-2 dbuf, Q from LDS)
    const unsigned short* Sb = ST + (((size_t)(b * NC + c)) << 16) + (size_t)(w * 64) * MM;
    s16x8 bs0[4], bs1[4];
#pragma unroll
    for (int t2 = 0; t2 < 4; ++t2)
        bs0[t2] = *(const s16x8*)(Sb + (size_t)(t2 * 16 + col) * MM + quad * 8);
#pragma unroll
    for (int ms = 0; ms < 8; ++ms) {
        if (ms < 7) {
#pragma unroll
            for (int t2 = 0; t2 < 4; ++t2)
                bs1[t2] = *(const s16x8*)(Sb + (size_t)(t2 * 16 + col) * MM + (ms + 1) * 32 + quad * 8);
        }
        s16x8 aq[4];
#pragma unroll
        for (int t = 0; t < 4; ++t)
            aq[t] = *(const s16x8*)&Qs[t * 16 + col][ms * 32 + quad * 8];
#pragma unroll
        for (int t2 = 0; t2 < 4; ++t2)
#pragma unroll
            for (int t = 0; t < 4; ++t)
                oacc[t][t2] = MFMA16(aq[t], bs0[t2], oacc[t][t2]);
#pragma unroll
        for (int t2 = 0; t2 < 4; ++t2) bs0[t2] = bs1[t2];
    }
    // denominator z-dot from LDS Qs
    {
        const int i = tid & 63;
        const int seg = tid >> 6;
        float d = 0.f;
#pragma unroll
        for (int g = 0; g < 8; ++g) {
            const s16x8 qv8 = *(const s16x8*)&Qs[i][seg * 64 + g * 8];
#pragma unroll
            for (int x = 0; x < 8; ++x)
                d = fmaf(bf2f((unsigned short)qv8[x]), z_s[seg * 64 + g * 8 + x], d);
        }
        red[i][64 + seg] = d;
    }
    __syncthreads();
    if (tid < 64) {
        float s = 0.f;
#pragma unroll
        for (int j = 0; j < 68; ++j) s += red[tid][j];
        den_s[tid] = fmaxf(s, 1e-6f);
    }
    __syncthreads();
#pragma unroll
    for (int t = 0; t < 4; ++t)
#pragma unroll
        for (int r = 0; r < 4; ++r) {
            const int i_loc = t * 16 + quad * 4 + r;
            const float invd = 1.0f / den_s[i_loc];
#pragma unroll
            for (int t2 = 0; t2 < 4; ++t2)
                Out[(chunk_row + it * 64 + i_loc) * DV + w * 64 + t2 * 16 + col] = oacc[t][t2][r] * invd;
        }
}

extern "C" void kernel_launch(void* const* d_in, const int* in_sizes, int n_in,
                              void* d_out, int out_size, void* d_ws, size_t ws_size,
                              hipStream_t stream)
{
    const float* Q  = (const float*)d_in[0];
    const float* K  = (const float*)d_in[1];
    const float* V  = (const float*)d_in[2];
    const float* Om = (const float*)d_in[3];
    float* out = (float*)d_out;

    const size_t NM = (size_t)BN * NN * MM;
    unsigned short* PhiQ  = (unsigned short*)d_ws;
    unsigned short* PhiK  = PhiQ + NM;
    unsigned short* PhiKT = PhiK + NM;
    unsigned short* VT    = PhiKT + NM;
    unsigned short* ST    = VT + NM;
    unsigned short* OmH   = ST + (size_t)BN * NC * DV * MM;
    unsigned short* OmL   = OmH + (size_t)MM * DD;
    float* Z = (float*)(OmL + (size_t)MM * DD);

    hipMemsetAsync(Z, 0, (size_t)BN * NC * MM * sizeof(float), stream);
    omconv<<<dim3(64), dim3(256), 0, stream>>>(Om, OmH, OmL);
    phi_mfma<false><<<dim3((BN * NN) / 64), dim3(256), 0, stream>>>(Q, OmH, OmL, PhiQ, nullptr, nullptr);
    phi_mfma<true><<<dim3((BN * NN) / 64), dim3(256), 0, stream>>>(K, OmH, OmL, PhiK, PhiKT, Z);
    transpose_v<<<dim3((BN * NN) / 64 * 4), dim3(256), 0, stream>>>(V, VT);
    state_mfma<<<dim3(BN * NC * 4), dim3(256), 0, stream>>>(VT, PhiKT, ST);
    prefix2<<<dim3((BN * DV * MM) / 256), dim3(256), 0, stream>>>(ST, Z);
    out_mfma<<<dim3(BN * NC * 4), dim3(256), 0, stream>>>(PhiQ, PhiK, VT, ST, Z, out);
}

// Round 5
// 245.821 us; speedup vs baseline: 3.8059x; 1.0315x over previous
//
#include <hip/hip_runtime.h>

#define BN 8
#define NN 4096
#define DD 256   // D_FULL
#define MM 256   // num features
#define DV 256   // value dim
#define CHUNK 256
#define NC (NN / CHUNK)   // 16 chunks per batch

using f32x4 = __attribute__((ext_vector_type(4))) float;
using s16x8 = __attribute__((ext_vector_type(8))) short;

#define MFMA16(a, b, c) __builtin_amdgcn_mfma_f32_16x16x32_bf16(a, b, c, 0, 0, 0)

__device__ __forceinline__ unsigned short f2bf(float x) {
    union { float f; unsigned int u; } v; v.f = x;
    unsigned int r = v.u + 0x7FFF + ((v.u >> 16) & 1);   // RNE
    return (unsigned short)(r >> 16);
}
__device__ __forceinline__ float bf2f(unsigned short u) {
    union { unsigned int u; float f; } v; v.u = ((unsigned int)u) << 16;
    return v.f;
}

// fp32 -> (hi: truncated bf16, lo: RNE bf16 of remainder); hi+lo ~ 2^-17 rel err
__device__ __forceinline__ void split8(const float4 xa, const float4 xb,
                                       s16x8& ah, s16x8& al)
{
    const float xs[8] = {xa.x, xa.y, xa.z, xa.w, xb.x, xb.y, xb.z, xb.w};
#pragma unroll
    for (int j = 0; j < 8; ++j) {
        union { float f; unsigned u; } v; v.f = xs[j];
        const unsigned hm = v.u & 0xFFFF0000u;
        union { unsigned u; float f; } hv; hv.u = hm;
        ah[j] = (short)(hm >> 16);
        al[j] = (short)f2bf(xs[j] - hv.f);
    }
}

// ---------------------------------------------------------------------------
// K0: omega fp32 [256][256] -> hi/lo bf16 pair (row-major, B-operand ready)
// ---------------------------------------------------------------------------
__global__ __launch_bounds__(256) void omconv(
    const float* __restrict__ Om, unsigned short* __restrict__ OmH,
    unsigned short* __restrict__ OmL)
{
    const int i = blockIdx.x * 256 + threadIdx.x;
    const float4 v = *(const float4*)(Om + (size_t)i * 4);
    const float xs[4] = {v.x, v.y, v.z, v.w};
    unsigned short h[4], l[4];
#pragma unroll
    for (int j = 0; j < 4; ++j) {
        h[j] = f2bf(xs[j]);
        l[j] = f2bf(xs[j] - bf2f(h[j]));
    }
    *(uint2*)(OmH + (size_t)i * 4) = *(uint2*)h;
    *(uint2*)(OmL + (size_t)i * 4) = *(uint2*)l;
}

// ---------------------------------------------------------------------------
// K1 (fused Q+K): phi = exp(X@Om^T - rowmax)/16 via bf16 MFMA hi/lo (3 terms).
// v3: X staged raw fp32 via global_load_lds DMA (1 row = 1 instr, pitch 1040B
// for conflict-free frag reads), hi/lo conversion at frag-read time.
// Blocks 0..511 = K path (also writes PhiT + per-chunk Z); 512..1023 = Q path.
// ---------------------------------------------------------------------------
__global__ __launch_bounds__(256) void phi_fused(
    const float* __restrict__ Qp, const float* __restrict__ Kp,
    const unsigned short* __restrict__ OmH, const unsigned short* __restrict__ OmL,
    unsigned short* __restrict__ PhiQ, unsigned short* __restrict__ PhiK,
    unsigned short* __restrict__ PhiT, float* __restrict__ Zp)
{
    const int tid = threadIdx.x;
    const int w = tid >> 6;
    const int lane = tid & 63;
    const int col = lane & 15, quad = lane >> 4;
    const bool kpath = blockIdx.x < 512;
    const int id = kpath ? blockIdx.x : (blockIdx.x - 512);
    const float* __restrict__ X = kpath ? Kp : Qp;
    unsigned short* __restrict__ Phi = kpath ? PhiK : PhiQ;
    const long r0 = (long)id * 64;

    __shared__ __align__(16) char lds[66560];     // X[64] rows @ pitch 1040 B
    __shared__ float rowmax_s[64];
    float (*Xs)[260] = (float(*)[260])lds;                    // pitch 260 f32
    unsigned short (*P)[264] = (unsigned short(*)[264])lds;   // epilogue alias
    unsigned int* P32 = (unsigned int*)lds;
    float (*red)[67] = (float(*)[67])(lds + 34048);           // epilogue alias

    // ---- DMA stage: row r (1 KB) -> Xs[r][.], lane i supplies +i*16 B
    {
        const float* gbase = X + r0 * DD + (size_t)lane * 4;
#pragma unroll
        for (int j = 0; j < 16; ++j) {
            const int row = w * 16 + j;
            __builtin_amdgcn_global_load_lds(
                (const __attribute__((address_space(1))) unsigned int*)(gbase + (size_t)row * DD),
                (__attribute__((address_space(3))) unsigned int*)(&Xs[row][0]),
                16, 0, 0);
        }
    }
    __syncthreads();

    // ---- K loop: LDS fp32 A-frags (convert in regs), dbuf Om B-frags
    f32x4 acc[4][4] = {};
    s16x8 bh0[4], bl0[4], bh1[4], bl1[4];
#pragma unroll
    for (int ct = 0; ct < 4; ++ct) {
        const size_t off = (size_t)(w * 64 + ct * 16 + col) * DD + quad * 8;
        bh0[ct] = *(const s16x8*)(OmH + off);
        bl0[ct] = *(const s16x8*)(OmL + off);
    }
#pragma unroll
    for (int kt = 0; kt < 8; ++kt) {
        if (kt < 7) {
#pragma unroll
            for (int ct = 0; ct < 4; ++ct) {
                const size_t off = (size_t)(w * 64 + ct * 16 + col) * DD + (kt + 1) * 32 + quad * 8;
                bh1[ct] = *(const s16x8*)(OmH + off);
                bl1[ct] = *(const s16x8*)(OmL + off);
            }
        }
#pragma unroll
        for (int t = 0; t < 4; ++t) {
            const float4 xa = *(const float4*)&Xs[t * 16 + col][kt * 32 + quad * 8];
            const float4 xb = *(const float4*)&Xs[t * 16 + col][kt * 32 + quad * 8 + 4];
            s16x8 ah, al;
            split8(xa, xb, ah, al);
#pragma unroll
            for (int ct = 0; ct < 4; ++ct) {
                acc[t][ct] = MFMA16(ah, bh0[ct], acc[t][ct]);
                acc[t][ct] = MFMA16(ah, bl0[ct], acc[t][ct]);
                acc[t][ct] = MFMA16(al, bh0[ct], acc[t][ct]);
            }
        }
#pragma unroll
        for (int ct = 0; ct < 4; ++ct) { bh0[ct] = bh1[ct]; bl0[ct] = bl1[ct]; }
    }

    // ---- row max over 256 cols (red aliases Xs: barrier first)
    __syncthreads();
#pragma unroll
    for (int t = 0; t < 4; ++t)
#pragma unroll
        for (int r = 0; r < 4; ++r) {
            float m = acc[t][0][r];
#pragma unroll
            for (int ct = 1; ct < 4; ++ct) m = fmaxf(m, acc[t][ct][r]);
            red[t * 16 + quad * 4 + r][w * 16 + col] = m;
        }
    __syncthreads();
    if (tid < 64) {
        float m = red[tid][0];
#pragma unroll
        for (int j = 1; j < 64; ++j) m = fmaxf(m, red[tid][j]);
        rowmax_s[tid] = m;
    }
    __syncthreads();

    // ---- exp epilogue -> P[n][m] bf16 (P aliases Xs: dead)
#pragma unroll
    for (int t = 0; t < 4; ++t)
#pragma unroll
        for (int r = 0; r < 4; ++r) {
            const int n = t * 16 + quad * 4 + r;
            const float rm = rowmax_s[n];
#pragma unroll
            for (int ct = 0; ct < 4; ++ct) {
                const float val = __expf(acc[t][ct][r] - rm) * 0.0625f;
                const unsigned u = (unsigned)f2bf(val);
                const unsigned up = (unsigned)__shfl_xor((int)u, 1);
                if ((col & 1) == 0)
                    P32[n * 132 + w * 32 + ct * 8 + (col >> 1)] = u | (up << 16);
            }
        }
    __syncthreads();

    // ---- Phi row-major vectorized stores
    {
        const int t7 = tid & 7;
        const int nb = tid >> 3;
#pragma unroll
        for (int p2 = 0; p2 < 2; ++p2) {
            const int n = p2 * 32 + nb;
#pragma unroll
            for (int s = 0; s < 4; ++s)
                *(uint4*)(Phi + (r0 + n) * MM + t7 * 8 + s * 64) =
                    *(const uint4*)&P[n][t7 * 8 + s * 64];
        }
    }

    if (kpath) {
        const int b = id >> 6;
        const int c = (id >> 2) & 15;
        const int n0 = (int)(r0 & (NN - 1));
        const int m0 = tid & 31;
        const int nsub = tid >> 5;
#pragma unroll
        for (int mi = 0; mi < 8; ++mi) {
            const int m = mi * 32 + m0;
            unsigned short u[8];
#pragma unroll
            for (int j = 0; j < 8; ++j) u[j] = P[nsub * 8 + j][m];
            *(uint4*)(PhiT + ((size_t)b * MM + m) * NN + n0 + nsub * 8) = *(uint4*)u;
        }
        float z = 0.f;
#pragma unroll
        for (int n = 0; n < 64; ++n) z += bf2f(P[n][tid]);
        atomicAdd(&Zp[((b * NC + c) << 8) + tid], z);
    }
}

// ---------------------------------------------------------------------------
// T1: V fp32 [B*N][256] -> VT bf16 [B][256][N]
// ---------------------------------------------------------------------------
__global__ __launch_bounds__(256) void transpose_v(
    const float* __restrict__ V, unsigned short* __restrict__ VT)
{
    const int tid = threadIdx.x;
    const int ct = blockIdx.x & 3;
    const long r0 = (long)(blockIdx.x >> 2) * 64;
    const int b = (int)(r0 >> 12);
    const int n0 = (int)(r0 & (NN - 1));
    __shared__ unsigned short T[64][72];
    const int rr = tid >> 4, cs = tid & 15;
#pragma unroll
    for (int p = 0; p < 4; ++p) {
        const int r = p * 16 + rr;
        const float4 v = *(const float4*)(V + (r0 + r) * DV + ct * 64 + cs * 4);
        T[cs * 4 + 0][r] = f2bf(v.x); T[cs * 4 + 1][r] = f2bf(v.y);
        T[cs * 4 + 2][r] = f2bf(v.z); T[cs * 4 + 3][r] = f2bf(v.w);
    }
    __syncthreads();
    const int cl = tid >> 3, ns = tid & 7;
#pragma unroll
    for (int p = 0; p < 2; ++p) {
        const int c = p * 32 + cl;
        *(uint4*)(VT + ((size_t)b * DV + ct * 64 + c) * NN + n0 + ns * 8) = *(uint4*)&T[c][ns * 8];
    }
}

// ---------------------------------------------------------------------------
// K2: per-chunk ST_c[dv][m] = sum_kr V[kr][dv]*phi_k[kr][m]  (bf16 MFMA)
// depth-2 register dbuf, XCD-grouped grid (q = hi bits), 3 waves/EU.
// ---------------------------------------------------------------------------
__global__ __launch_bounds__(256, 3) void state_mfma(
    const unsigned short* __restrict__ VT, const unsigned short* __restrict__ PkT,
    unsigned short* __restrict__ ST)
{
    const int tid = threadIdx.x;
    const int w = tid >> 6;
    const int lane = tid & 63;
    const int col = lane & 15, quad = lane >> 4;
    const int q  = blockIdx.x >> 7;
    const int bc = blockIdx.x & 127;
    const int c  = bc & 15;
    const int b  = bc >> 4;
    const int dv0 = (q & 1) * 128 + (w & 1) * 64;
    const int m0  = (q >> 1) * 128 + (w >> 1) * 64;
    const unsigned short* Ab = VT  + (size_t)b * DV * NN + (size_t)c * CHUNK;
    const unsigned short* Bb = PkT + (size_t)b * MM * NN + (size_t)c * CHUNK;

    f32x4 acc[4][4] = {};
    s16x8 a0[4], b0[4], a1[4], b1[4];
#pragma unroll
    for (int t = 0; t < 4; ++t) {
        a0[t] = *(const s16x8*)(Ab + (size_t)(dv0 + t * 16 + col) * NN + quad * 8);
        b0[t] = *(const s16x8*)(Bb + (size_t)(m0 + t * 16 + col) * NN + quad * 8);
    }
#pragma unroll
    for (int kt = 0; kt < 8; ++kt) {
        if (kt < 7) {
#pragma unroll
            for (int t = 0; t < 4; ++t) {
                a1[t] = *(const s16x8*)(Ab + (size_t)(dv0 + t * 16 + col) * NN + (kt + 1) * 32 + quad * 8);
                b1[t] = *(const s16x8*)(Bb + (size_t)(m0 + t * 16 + col) * NN + (kt + 1) * 32 + quad * 8);
            }
        }
#pragma unroll
        for (int i = 0; i < 4; ++i)
#pragma unroll
            for (int j = 0; j < 4; ++j) acc[i][j] = MFMA16(a0[i], b0[j], acc[i][j]);
#pragma unroll
        for (int t = 0; t < 4; ++t) { a0[t] = a1[t]; b0[t] = b1[t]; }
    }
    unsigned short* Sb = ST + (((size_t)(b * NC + c)) << 16);
#pragma unroll
    for (int i = 0; i < 4; ++i)
#pragma unroll
        for (int j = 0; j < 4; ++j)
#pragma unroll
            for (int r = 0; r < 4; ++r)
                Sb[(dv0 + i * 16 + quad * 4 + r) * MM + m0 + j * 16 + col] = f2bf(acc[i][j][r]);
}

// ---------------------------------------------------------------------------
// K3: in-place exclusive prefix over chunks: ST (bf16), Z (fp32)
// ---------------------------------------------------------------------------
__global__ __launch_bounds__(256) void prefix2(
    unsigned short* __restrict__ ST, float* __restrict__ Z)
{
    const long idx = (long)blockIdx.x * 256 + threadIdx.x;
    const int b = (int)(idx >> 16);
    const int r = (int)(idx & 65535);
    float run = 0.f;
#pragma unroll
    for (int c = 0; c < NC; ++c) {
        const size_t off = (((size_t)(b * NC + c)) << 16) + r;
        const float v = bf2f(ST[off]);
        ST[off] = f2bf(run);
        run += v;
    }
    if (idx < BN * MM) {
        const int b2 = (int)(idx >> 8);
        const int m = (int)(idx & 255);
        float rz = 0.f;
#pragma unroll
        for (int c = 0; c < NC; ++c) {
            const size_t off = (size_t)(b2 * NC + c) * MM + m;
            const float v = Z[off];
            Z[off] = rz;
            rz += v;
        }
    }
}

// ---------------------------------------------------------------------------
// K4: Q tile in LDS (staged once); batched/pipelined global frag loads.
// out = (intra causal A@V + phi_q@S_pre) / (rowsum(A) + phi_q.z_pre)
// ---------------------------------------------------------------------------
__global__ __launch_bounds__(256) void out_mfma(
    const unsigned short* __restrict__ PhiQ, const unsigned short* __restrict__ PhiK,
    const unsigned short* __restrict__ VT, const unsigned short* __restrict__ ST,
    const float* __restrict__ Z, float* __restrict__ Out)
{
    const int tid = threadIdx.x;
    const int w = tid >> 6;
    const int lane = tid & 63;
    const int col = lane & 15, quad = lane >> 4;
    const int it = 3 - (blockIdx.x >> 7);
    const int low = blockIdx.x & 127;
    const int c  = low & 15;
    const int b  = low >> 4;
    const size_t chunk_row = (size_t)b * NN + (size_t)c * CHUNK;
    const unsigned short* Qrow = PhiQ + (chunk_row + it * 64) * MM;

    __shared__ unsigned short Qs[64][264];
    __shared__ unsigned short A_s[64][72];
    __shared__ float red[64][68];
    __shared__ float z_s[256];
    __shared__ float den_s[64];

    const float zval = Z[((size_t)(b * NC + c) << 8) + tid];
    s16x8 bk0[8], bk1[8];
#pragma unroll
    for (int ms = 0; ms < 8; ++ms)
        bk0[ms] = *(const s16x8*)(PhiK + (chunk_row)*MM + (size_t)(w * 16 + col) * MM + ms * 32 + quad * 8);
    uint4 qv[8];
#pragma unroll
    for (int i = 0; i < 8; ++i)
        qv[i] = *((const uint4*)Qrow + i * 256 + tid);
    z_s[tid] = zval;
#pragma unroll
    for (int i = 0; i < 8; ++i) {
        const int f = i * 256 + tid;
        *(uint4*)&Qs[f >> 5][(f & 31) * 8] = qv[i];
    }
    __syncthreads();

    f32x4 oacc[4][4] = {};
    float rsum[4][4] = {};

    for (int jt = 0; jt <= it; ++jt) {
        s16x8 bv[8];
        const unsigned short* Vbase = VT + ((size_t)b * DV + w * 64) * NN + (size_t)c * CHUNK + jt * 64;
#pragma unroll
        for (int ks2 = 0; ks2 < 2; ++ks2)
#pragma unroll
            for (int t2 = 0; t2 < 4; ++t2)
                bv[ks2 * 4 + t2] = *(const s16x8*)(Vbase + (size_t)(t2 * 16 + col) * NN + ks2 * 32 + quad * 8);
        f32x4 accA[4] = {};
#pragma unroll
        for (int ms = 0; ms < 8; ++ms)
#pragma unroll
            for (int t = 0; t < 4; ++t) {
                const s16x8 aq = *(const s16x8*)&Qs[t * 16 + col][ms * 32 + quad * 8];
                accA[t] = MFMA16(aq, bk0[ms], accA[t]);
            }
        if (jt < it) {
            const unsigned short* Krn = PhiK + (chunk_row + (jt + 1) * 64) * MM;
#pragma unroll
            for (int ms = 0; ms < 8; ++ms)
                bk1[ms] = *(const s16x8*)(Krn + (size_t)(w * 16 + col) * MM + ms * 32 + quad * 8);
        }
        __syncthreads();
#pragma unroll
        for (int t = 0; t < 4; ++t)
#pragma unroll
            for (int r = 0; r < 4; ++r) {
                const int i_loc = t * 16 + quad * 4 + r;
                const int j_loc = w * 16 + col;
                float v = (jt * 64 + j_loc <= it * 64 + i_loc) ? accA[t][r] : 0.f;
                rsum[t][r] += v;
                A_s[i_loc][j_loc] = f2bf(v);
            }
        __syncthreads();
#pragma unroll
        for (int ks2 = 0; ks2 < 2; ++ks2) {
            s16x8 av[4];
#pragma unroll
            for (int t = 0; t < 4; ++t)
                av[t] = *(const s16x8*)&A_s[t * 16 + col][ks2 * 32 + quad * 8];
#pragma unroll
            for (int t2 = 0; t2 < 4; ++t2)
#pragma unroll
                for (int t = 0; t < 4; ++t)
                    oacc[t][t2] = MFMA16(av[t], bv[ks2 * 4 + t2], oacc[t][t2]);
        }
#pragma unroll
        for (int ms = 0; ms < 8; ++ms) bk0[ms] = bk1[ms];
    }
#pragma unroll
    for (int t = 0; t < 4; ++t)
#pragma unroll
        for (int r = 0; r < 4; ++r)
            red[t * 16 + quad * 4 + r][w * 16 + col] = rsum[t][r];

    const unsigned short* Sb = ST + (((size_t)(b * NC + c)) << 16) + (size_t)(w * 64) * MM;
    s16x8 bs0[4], bs1[4];
#pragma unroll
    for (int t2 = 0; t2 < 4; ++t2)
        bs0[t2] = *(const s16x8*)(Sb + (size_t)(t2 * 16 + col) * MM + quad * 8);
#pragma unroll
    for (int ms = 0; ms < 8; ++ms) {
        if (ms < 7) {
#pragma unroll
            for (int t2 = 0; t2 < 4; ++t2)
                bs1[t2] = *(const s16x8*)(Sb + (size_t)(t2 * 16 + col) * MM + (ms + 1) * 32 + quad * 8);
        }
        s16x8 aq[4];
#pragma unroll
        for (int t = 0; t < 4; ++t)
            aq[t] = *(const s16x8*)&Qs[t * 16 + col][ms * 32 + quad * 8];
#pragma unroll
        for (int t2 = 0; t2 < 4; ++t2)
#pragma unroll
            for (int t = 0; t < 4; ++t)
                oacc[t][t2] = MFMA16(aq[t], bs0[t2], oacc[t][t2]);
#pragma unroll
        for (int t2 = 0; t2 < 4; ++t2) bs0[t2] = bs1[t2];
    }
    {
        const int i = tid & 63;
        const int seg = tid >> 6;
        float d = 0.f;
#pragma unroll
        for (int g = 0; g < 8; ++g) {
            const s16x8 qv8 = *(const s16x8*)&Qs[i][seg * 64 + g * 8];
#pragma unroll
            for (int x = 0; x < 8; ++x)
                d = fmaf(bf2f((unsigned short)qv8[x]), z_s[seg * 64 + g * 8 + x], d);
        }
        red[i][64 + seg] = d;
    }
    __syncthreads();
    if (tid < 64) {
        float s = 0.f;
#pragma unroll
        for (int j = 0; j < 68; ++j) s += red[tid][j];
        den_s[tid] = fmaxf(s, 1e-6f);
    }
    __syncthreads();
#pragma unroll
    for (int t = 0; t < 4; ++t)
#pragma unroll
        for (int r = 0; r < 4; ++r) {
            const int i_loc = t * 16 + quad * 4 + r;
            const float invd = 1.0f / den_s[i_loc];
#pragma unroll
            for (int t2 = 0; t2 < 4; ++t2)
                Out[(chunk_row + it * 64 + i_loc) * DV + w * 64 + t2 * 16 + col] = oacc[t][t2][r] * invd;
        }
}

extern "C" void kernel_launch(void* const* d_in, const int* in_sizes, int n_in,
                              void* d_out, int out_size, void* d_ws, size_t ws_size,
                              hipStream_t stream)
{
    const float* Q  = (const float*)d_in[0];
    const float* K  = (const float*)d_in[1];
    const float* V  = (const float*)d_in[2];
    const float* Om = (const float*)d_in[3];
    float* out = (float*)d_out;

    const size_t NM = (size_t)BN * NN * MM;
    unsigned short* PhiQ  = (unsigned short*)d_ws;
    unsigned short* PhiK  = PhiQ + NM;
    unsigned short* PhiKT = PhiK + NM;
    unsigned short* VT    = PhiKT + NM;
    unsigned short* ST    = VT + NM;
    unsigned short* OmH   = ST + (size_t)BN * NC * DV * MM;
    unsigned short* OmL   = OmH + (size_t)MM * DD;
    float* Z = (float*)(OmL + (size_t)MM * DD);

    hipMemsetAsync(Z, 0, (size_t)BN * NC * MM * sizeof(float), stream);
    omconv<<<dim3(64), dim3(256), 0, stream>>>(Om, OmH, OmL);
    phi_fused<<<dim3(1024), dim3(256), 0, stream>>>(Q, K, OmH, OmL, PhiQ, PhiK, PhiKT, Z);
    transpose_v<<<dim3((BN * NN) / 64 * 4), dim3(256), 0, stream>>>(V, VT);
    state_mfma<<<dim3(BN * NC * 4), dim3(256), 0, stream>>>(VT, PhiKT, ST);
    prefix2<<<dim3((BN * DV * MM) / 256), dim3(256), 0, stream>>>(ST, Z);
    out_mfma<<<dim3(BN * NC * 4), dim3(256), 0, stream>>>(PhiQ, PhiK, VT, ST, Z, out);
}